// Round 11
// baseline (225.135 us; speedup 1.0000x reference)
//
#include <hip/hip_runtime.h>
#include <hip/hip_bf16.h>
#include <cstddef>
#include <cstdint>

// Problem constants
#define BB 8
#define HH 16
#define TT 128
#define SS 512
#define DD 1024
#define VV 32000
#define MM (BB * TT)   // 1024 output rows

typedef float f32x4 __attribute__((ext_vector_type(4)));
typedef short short8v __attribute__((ext_vector_type(8)));
typedef unsigned short ushort8v __attribute__((ext_vector_type(8)));

__device__ __forceinline__ unsigned short f2bf(float x) {
    __hip_bfloat16 h = __float2bfloat16(x);
    return __builtin_bit_cast(unsigned short, h);
}
__device__ __forceinline__ float bf2f(unsigned short u) {
    unsigned int x = ((unsigned int)u) << 16;
    return __builtin_bit_cast(float, x);
}

__device__ __forceinline__ float wave_sum(float v) {
#pragma unroll
    for (int o = 1; o < 64; o <<= 1) v += __shfl_xor(v, o);
    return v;
}
__device__ __forceinline__ float wave_max(float v) {
#pragma unroll
    for (int o = 1; o < 64; o <<= 1) v = fmaxf(v, __shfl_xor(v, o));
    return v;
}
__device__ __forceinline__ float block_sum(float v, float* red, int tid) {
    v = wave_sum(v);
    __syncthreads();
    if ((tid & 63) == 0) red[tid >> 6] = v;
    __syncthreads();
    return red[0] + red[1] + red[2] + red[3];
}
__device__ __forceinline__ float block_max(float v, float* red, int tid) {
    v = wave_max(v);
    __syncthreads();
    if ((tid & 63) == 0) red[tid >> 6] = v;
    __syncthreads();
    return fmaxf(fmaxf(red[0], red[1]), fmaxf(red[2], red[3]));
}

// ---------------- pos_map init + zg zero ----------------
__global__ void k_pm_init(int* pos_map, float* zg) {
    int i = blockIdx.x * 256 + threadIdx.x;
    if (i < BB * VV) pos_map[i] = 0x7fffffff;
    if (i < MM) zg[i] = 0.0f;
}

// ---------------- merged setup: pm_build | vecdots | cast-W | cast-A ----------------
// Region layout (512-thread blocks):
//   [0,8)        pm_build           (8 x 512 tokens)
//   [8,648)      vecdots, 8 rows/block (5120 rows)
//   [648,1160)   cast W_gen f32->bf16, grid-stride (512 blocks)  [if do_cast]
//   [1160,1192)  cast dec  f32->bf16, grid-stride (32 blocks)    [if do_cast]
__global__ __launch_bounds__(512) void k_setup(const int* __restrict__ src,
                                               int* __restrict__ pos_map,
                                               const float* __restrict__ memory,
                                               const float* __restrict__ dec,
                                               const float* __restrict__ wprob,
                                               float* __restrict__ mw,
                                               float* __restrict__ dw,
                                               const float* __restrict__ wgen,
                                               unsigned short* __restrict__ Wbf,
                                               unsigned short* __restrict__ Abf) {
    int blk = blockIdx.x, tid = threadIdx.x;
    if (blk < 8) {
        int tok = src[blk * SS + tid];
        atomicMin(&pos_map[blk * VV + tok], tid);
    } else if (blk < 648) {
        int row = (blk - 8) * 8 + (tid >> 6);
        int lane = tid & 63;
        const float4* srcv;
        const float4* wv;
        if (row < BB * SS) {
            srcv = reinterpret_cast<const float4*>(memory + (size_t)row * DD);
            wv = reinterpret_cast<const float4*>(wprob);
        } else {
            srcv = reinterpret_cast<const float4*>(dec + (size_t)(row - BB * SS) * DD);
            wv = reinterpret_cast<const float4*>(wprob + DD);
        }
        float sum = 0.f;
#pragma unroll
        for (int k = 0; k < 4; ++k) {
            int idx = lane + 64 * k;
            float4 a = srcv[idx];
            float4 w = wv[idx];
            sum += a.x * w.x + a.y * w.y + a.z * w.z + a.w * w.w;
        }
        sum = wave_sum(sum);
        if (lane == 0) {
            if (row < BB * SS) mw[row] = sum;
            else dw[row - BB * SS] = sum;
        }
    } else if (blk < 1160) {
        if (Wbf == nullptr) return;
        const int n8 = VV * DD / 8;
        for (int i = (blk - 648) * 512 + tid; i < n8; i += 512 * 512) {
            const float4* p = reinterpret_cast<const float4*>(wgen + (size_t)i * 8);
            float4 a = p[0], b = p[1];
            ushort8v u;
            u[0] = f2bf(a.x); u[1] = f2bf(a.y); u[2] = f2bf(a.z); u[3] = f2bf(a.w);
            u[4] = f2bf(b.x); u[5] = f2bf(b.y); u[6] = f2bf(b.z); u[7] = f2bf(b.w);
            *reinterpret_cast<ushort8v*>(Wbf + (size_t)i * 8) = u;
        }
    } else {
        if (Abf == nullptr) return;
        const int n8 = MM * DD / 8;
        for (int i = (blk - 1160) * 512 + tid; i < n8; i += 32 * 512) {
            const float4* p = reinterpret_cast<const float4*>(dec + (size_t)i * 8);
            float4 a = p[0], b = p[1];
            ushort8v u;
            u[0] = f2bf(a.x); u[1] = f2bf(a.y); u[2] = f2bf(a.z); u[3] = f2bf(a.w);
            u[4] = f2bf(b.x); u[5] = f2bf(b.y); u[6] = f2bf(b.z); u[7] = f2bf(b.w);
            *reinterpret_cast<ushort8v*>(Abf + (size_t)i * 8) = u;
        }
    }
}

// ---------------- per-(b,t) row: attn mean, scatter, prob, copy-Z ----------------
__global__ __launch_bounds__(256) void k_row(const float* __restrict__ dattn,
                                             const int* __restrict__ src,
                                             const int* __restrict__ pos_map,
                                             const float* __restrict__ mw,
                                             const float* __restrict__ dw,
                                             const float* __restrict__ bprob,
                                             float* __restrict__ e_vals,
                                             float* __restrict__ prob,
                                             float* __restrict__ zc,
                                             float* __restrict__ c0) {
    int bt = blockIdx.x;
    int b = bt >> 7;
    int t = bt & 127;
    int tid = threadIdx.x;
    __shared__ float a_row[SS];
    __shared__ float vals[SS];
    __shared__ float red[4];

    // head mean, float2-vectorized: thread tid owns elems {2tid, 2tid+1}
    {
        const float2* base = reinterpret_cast<const float2*>(
            dattn + ((size_t)b * HH * TT + t) * SS) + tid;
        float sx = 0.f, sy = 0.f;
#pragma unroll
        for (int h = 0; h < HH; ++h) {
            float2 v = base[(size_t)h * (TT * SS / 2)];
            sx += v.x; sy += v.y;
        }
        a_row[2 * tid] = sx * 0.0625f;
        a_row[2 * tid + 1] = sy * 0.0625f;
        vals[2 * tid] = 0.f;
        vals[2 * tid + 1] = 0.f;
    }
    __syncthreads();
    for (int s = tid; s < SS; s += 256) {
        int rep = pos_map[b * VV + src[b * SS + s]];
        atomicAdd(&vals[rep], a_row[s]);
    }
    __syncthreads();
    float psum = 0.f;
    for (int s = tid; s < SS; s += 256) psum += a_row[s] * mw[b * SS + s];
    psum = block_sum(psum, red, tid);
    float z = psum + dw[bt] + bprob[0];
    float p = 1.0f / (1.0f + __expf(-z));
    float mxv = -3.4e38f;
    for (int s = tid; s < SS; s += 256) {
        int rep = pos_map[b * VV + src[b * SS + s]];
        if (rep == s) mxv = fmaxf(mxv, vals[s]);
    }
    mxv = block_max(mxv, red, tid);
    float m_c = fmaxf(0.0f, mxv);
    float sexp = 0.f, cnt = 0.f;
    for (int s = tid; s < SS; s += 256) {
        int rep = pos_map[b * VV + src[b * SS + s]];
        float e = 0.0f;
        if (rep == s) {
            e = __expf(vals[s] - m_c);
            sexp += e;
            cnt += 1.0f;
        }
        e_vals[(size_t)bt * SS + s] = e;
    }
    sexp = block_sum(sexp, red, tid);
    cnt = block_sum(cnt, red, tid);
    if (tid == 0) {
        prob[bt] = p;
        zc[bt] = ((float)VV - cnt) * __expf(-m_c) + sexp;
        c0[bt] = __expf(-m_c);
    }
}

// =====================================================================
// 128x256 bf16 MFMA GEMM, 8 waves (64x64), BK=32, TRIPLE buffer, 2-deep
// prefetch, counted vmcnt(3). Conflict-free XOR swizzle (R10-verified:
// 0 conflicts). THIS ROUND: no forced lgkmcnt(0)/sched_barrier before
// the MFMA cluster — compiler emits counted lgkm waits so the first
// MFMAs overlap the tail of the ds_reads (m97 evidence; rule-18 hazard
// only applies to inline-asm waits).
// =====================================================================
#define NKT 32          // K tiles = 1024/32
#define BUFE 12288      // elems per buffer: A 128*32=4096 + B 256*32=8192

#define AS1 __attribute__((address_space(1)))
#define AS3 __attribute__((address_space(3)))

template <int EPI>
__global__ __launch_bounds__(512, 4) void k_gemm_bf(const unsigned short* __restrict__ Abf,
                                                    const unsigned short* __restrict__ Wbf,
                                                    const float* __restrict__ bgen,
                                                    float* __restrict__ out,
                                                    unsigned short* __restrict__ ebuf,
                                                    float* __restrict__ zg) {
    __shared__ unsigned short lds[3 * BUFE];   // 72 KiB

    int tid = threadIdx.x;
    int p = blockIdx.x;
    // bijective XCD swizzle: 1000 = 8 * 125
    int wgid = (p & 7) * 125 + (p >> 3);
    int mt = wgid & 7, nt = wgid >> 3;   // consecutive wg share nt -> W L2 reuse
    int m0 = mt * 128, v0 = nt * 256;

    int lane = tid & 63, w = tid >> 6;
    int wm = w & 1, wn = w >> 1;         // wave owns 64(M) x 64(N)

    // staging: pre-swizzled source chunk ((tid&3)^((tid>>3)&3)), linear LDS dest
    int srow = tid >> 2;                 // 0..127
    int schunk = (tid & 3) ^ ((tid >> 3) & 3);
    const unsigned short* gA = Abf + (size_t)(m0 + srow) * DD + schunk * 8;
    const unsigned short* gB = Wbf + (size_t)(v0 + srow) * DD + schunk * 8;

    // per tile: 1 A-load + 2 B-loads per thread (vmcnt granularity = 3)
#define STAGE(T, BI) do {                                                              \
    size_t ko_ = (size_t)(T) * 32;                                                     \
    __builtin_amdgcn_global_load_lds(                                                  \
        (const AS1 void*)(gA + ko_),                                                   \
        (AS3 void*)(lds + (BI) * BUFE + tid * 8), 16, 0, 0);                           \
    __builtin_amdgcn_global_load_lds(                                                  \
        (const AS1 void*)(gB + ko_),                                                   \
        (AS3 void*)(lds + (BI) * BUFE + 4096 + tid * 8), 16, 0, 0);                    \
    __builtin_amdgcn_global_load_lds(                                                  \
        (const AS1 void*)(gB + (size_t)128 * DD + ko_),                                \
        (AS3 void*)(lds + (BI) * BUFE + 8192 + tid * 8), 16, 0, 0);                    \
} while (0)

    // fragment reads: row base multiple of 16 -> xr depends only on lr
    int lr = lane & 15, kg = lane >> 4;
    int xr = (lr >> 1) & 3;
    const unsigned short* arow = lds + (wm * 64 + lr) * 32 + ((kg ^ xr) << 3);
    const unsigned short* brow = lds + 4096 + (wn * 64 + lr) * 32 + ((kg ^ xr) << 3);

    f32x4 acc[4][4] = {};

    // one compute iteration on buffer BI, optional stage of tile T+2.
    // No explicit lgkm wait: MFMA(i,j) depends on af[i]/bfr[j] -> compiler
    // inserts counted lgkmcnt, overlapping first MFMAs with later reads.
#define ITER(T, BI, DO_STAGE, VM)  do {                                                \
    __builtin_amdgcn_s_barrier();                                                      \
    short8v af[4], bfr[4];                                                             \
    _Pragma("unroll")                                                                  \
    for (int i = 0; i < 4; ++i) {                                                      \
        af[i] = *reinterpret_cast<const short8v*>(arow + (BI) * BUFE + i * 512);       \
        bfr[i] = *reinterpret_cast<const short8v*>(brow + (BI) * BUFE + i * 512);      \
    }                                                                                  \
    if (DO_STAGE) STAGE((T) + 2, ((BI) + 2) % 3);                                      \
    __builtin_amdgcn_s_setprio(1);                                                     \
    _Pragma("unroll")                                                                  \
    for (int i = 0; i < 4; ++i)                                                        \
        _Pragma("unroll")                                                              \
        for (int j = 0; j < 4; ++j)                                                    \
            acc[i][j] = __builtin_amdgcn_mfma_f32_16x16x32_bf16(af[i], bfr[j], acc[i][j], 0, 0, 0); \
    __builtin_amdgcn_s_setprio(0);                                                     \
    if ((VM) == 3) asm volatile("s_waitcnt vmcnt(3)" ::: "memory");                    \
    else if ((VM) == 0) asm volatile("s_waitcnt vmcnt(0)" ::: "memory");               \
} while (0)

    // prologue: stage tiles 0,1; wait tile 0 (3 newest = tile 1 still in flight)
    STAGE(0, 0);
    STAGE(1, 1);
    asm volatile("s_waitcnt vmcnt(3)" ::: "memory");

    for (int t = 0; t < NKT - 2; t += 3) {
        ITER(t + 0, 0, true, 3);
        ITER(t + 1, 1, true, 3);
        ITER(t + 2, 2, true, 3);
    }
    ITER(30, 0, false, 0);
    ITER(31, 1, false, -1);
#undef ITER
#undef STAGE

    // ---- epilogue: bias + exp + store + per-row exp-sum atomics
    int colb = lane & 15, rgrp = lane >> 4;
#pragma unroll
    for (int i = 0; i < 4; ++i) {
        float es0 = 0.f, es1 = 0.f, es2 = 0.f, es3 = 0.f;
        int gmb = m0 + wm * 64 + i * 16 + rgrp * 4;
#pragma unroll
        for (int j = 0; j < 4; ++j) {
            int gv = v0 + wn * 64 + j * 16 + colb;
            float bgj = bgen[gv];
            float v0f = acc[i][j][0] + bgj;
            float v1f = acc[i][j][1] + bgj;
            float v2f = acc[i][j][2] + bgj;
            float v3f = acc[i][j][3] + bgj;
            float e0 = __expf(v0f), e1 = __expf(v1f), e2 = __expf(v2f), e3 = __expf(v3f);
            if constexpr (EPI == 1) {
                ebuf[(size_t)(gmb + 0) * VV + gv] = f2bf(e0);
                ebuf[(size_t)(gmb + 1) * VV + gv] = f2bf(e1);
                ebuf[(size_t)(gmb + 2) * VV + gv] = f2bf(e2);
                ebuf[(size_t)(gmb + 3) * VV + gv] = f2bf(e3);
            } else {
                out[(size_t)(gmb + 0) * VV + gv] = v0f;
                out[(size_t)(gmb + 1) * VV + gv] = v1f;
                out[(size_t)(gmb + 2) * VV + gv] = v2f;
                out[(size_t)(gmb + 3) * VV + gv] = v3f;
            }
            es0 += e0; es1 += e1; es2 += e2; es3 += e3;
        }
        float es[4] = {es0, es1, es2, es3};
#pragma unroll
        for (int rr = 0; rr < 4; ++rr) {
            float e = es[rr];
            e += __shfl_xor(e, 1); e += __shfl_xor(e, 2);
            e += __shfl_xor(e, 4); e += __shfl_xor(e, 8);
            if (colb == 0) atomicAdd(&zg[gmb + rr], e);
        }
    }
}

// ---------------- fallback GEMM (f32 inputs, in-register cast, 128^2) ----------------
#define FBb 128
#define FLDK 40

__global__ __launch_bounds__(256) void k_gemm_f32(const float* __restrict__ A,
                                                  const float* __restrict__ Wg,
                                                  const float* __restrict__ bgen,
                                                  float* __restrict__ out,
                                                  float* __restrict__ zg) {
    __shared__ unsigned short As[FBb * FLDK];
    __shared__ unsigned short Bs[FBb * FLDK];
    int tid = threadIdx.x;
    int bid = blockIdx.x;
    int mt = bid & 7;
    int nt = bid >> 3;
    int m0 = mt * FBb, v0 = nt * FBb;
    int lane = tid & 63, wid = tid >> 6;
    int wr = (wid >> 1) * 64, wc = (wid & 1) * 64;
    int lr = lane & 15, lk = (lane >> 4) << 3;
    int r = tid >> 1, c0 = (tid & 1) << 4;

    f32x4 acc[4][4] = {};

    for (int k0 = 0; k0 < DD; k0 += 32) {
        {
            const float4* pa = reinterpret_cast<const float4*>(A + (size_t)(m0 + r) * DD + k0 + c0);
            float4 x0 = pa[0], x1 = pa[1], x2 = pa[2], x3 = pa[3];
            ushort8v u0, u1;
            u0[0] = f2bf(x0.x); u0[1] = f2bf(x0.y); u0[2] = f2bf(x0.z); u0[3] = f2bf(x0.w);
            u0[4] = f2bf(x1.x); u0[5] = f2bf(x1.y); u0[6] = f2bf(x1.z); u0[7] = f2bf(x1.w);
            u1[0] = f2bf(x2.x); u1[1] = f2bf(x2.y); u1[2] = f2bf(x2.z); u1[3] = f2bf(x2.w);
            u1[4] = f2bf(x3.x); u1[5] = f2bf(x3.y); u1[6] = f2bf(x3.z); u1[7] = f2bf(x3.w);
            *reinterpret_cast<ushort8v*>(&As[r * FLDK + c0]) = u0;
            *reinterpret_cast<ushort8v*>(&As[r * FLDK + c0 + 8]) = u1;

            const float4* pb = reinterpret_cast<const float4*>(Wg + (size_t)(v0 + r) * DD + k0 + c0);
            float4 y0 = pb[0], y1 = pb[1], y2 = pb[2], y3 = pb[3];
            ushort8v w0, w1;
            w0[0] = f2bf(y0.x); w0[1] = f2bf(y0.y); w0[2] = f2bf(y0.z); w0[3] = f2bf(y0.w);
            w0[4] = f2bf(y1.x); w0[5] = f2bf(y1.y); w0[6] = f2bf(y1.z); w0[7] = f2bf(y1.w);
            w1[0] = f2bf(y2.x); w1[1] = f2bf(y2.y); w1[2] = f2bf(y2.z); w1[3] = f2bf(y2.w);
            w1[4] = f2bf(y3.x); w1[5] = f2bf(y3.y); w1[6] = f2bf(y3.z); w1[7] = f2bf(y3.w);
            *reinterpret_cast<ushort8v*>(&Bs[r * FLDK + c0]) = w0;
            *reinterpret_cast<ushort8v*>(&Bs[r * FLDK + c0 + 8]) = w1;
        }
        __syncthreads();

        short8v af[4], bfr[4];
#pragma unroll
        for (int i = 0; i < 4; ++i)
            af[i] = *reinterpret_cast<const short8v*>(&As[(wr + i * 16 + lr) * FLDK + lk]);
#pragma unroll
        for (int j = 0; j < 4; ++j)
            bfr[j] = *reinterpret_cast<const short8v*>(&Bs[(wc + j * 16 + lr) * FLDK + lk]);
#pragma unroll
        for (int i = 0; i < 4; ++i)
#pragma unroll
            for (int j = 0; j < 4; ++j)
                acc[i][j] = __builtin_amdgcn_mfma_f32_16x16x32_bf16(af[i], bfr[j], acc[i][j], 0, 0, 0);
        __syncthreads();
    }

    int colb = lane & 15;
    int rgrp = lane >> 4;
#pragma unroll
    for (int i = 0; i < 4; ++i) {
        float es0 = 0.f, es1 = 0.f, es2 = 0.f, es3 = 0.f;
        int gmb = m0 + wr + i * 16 + rgrp * 4;
#pragma unroll
        for (int j = 0; j < 4; ++j) {
            int gv = v0 + wc + j * 16 + colb;
            float bgj = bgen[gv];
            float v0f = acc[i][j][0] + bgj;
            float v1f = acc[i][j][1] + bgj;
            float v2f = acc[i][j][2] + bgj;
            float v3f = acc[i][j][3] + bgj;
            out[(size_t)(gmb + 0) * VV + gv] = v0f;
            out[(size_t)(gmb + 1) * VV + gv] = v1f;
            out[(size_t)(gmb + 2) * VV + gv] = v2f;
            out[(size_t)(gmb + 3) * VV + gv] = v3f;
            es0 += __expf(v0f); es1 += __expf(v1f);
            es2 += __expf(v2f); es3 += __expf(v3f);
        }
        float es[4] = {es0, es1, es2, es3};
#pragma unroll
        for (int rr = 0; rr < 4; ++rr) {
            float e = es[rr];
            e += __shfl_xor(e, 1); e += __shfl_xor(e, 2);
            e += __shfl_xor(e, 4); e += __shfl_xor(e, 8);
            if (colb == 0) atomicAdd(&zg[gmb + rr], e);
        }
    }
}

// ---------------- final combine into d_out ----------------
template <int RD16>
__global__ __launch_bounds__(256) void k_final(float* __restrict__ gen,
                                               const unsigned short* __restrict__ ebuf,
                                               const int* __restrict__ pos_map,
                                               const float* __restrict__ e_vals,
                                               const float* __restrict__ prob,
                                               const float* __restrict__ zc,
                                               const float* __restrict__ c0,
                                               const float* __restrict__ zg) {
    int m = blockIdx.x;
    int b = m >> 7;
    int tid = threadIdx.x;
    float p = prob[m];
    float A1 = p / zg[m];
    float A2 = (1.0f - p) / zc[m];
    float cc = c0[m];
    const float* ev = e_vals + (size_t)m * SS;
    float4* row = reinterpret_cast<float4*>(gen + (size_t)m * VV);
    const int4* pm = reinterpret_cast<const int4*>(pos_map + b * VV);
    if constexpr (RD16 == 1) {
        const ushort8v* erow = reinterpret_cast<const ushort8v*>(ebuf + (size_t)m * VV);
        for (int i = tid; i < VV / 8; i += 256) {
            ushort8v ee = erow[i];
            int4 rp0 = pm[2 * i], rp1 = pm[2 * i + 1];
            float4 o0, o1;
            o0.x = __logf(A1 * bf2f(ee[0]) + A2 * ((rp0.x < SS) ? ev[rp0.x] : cc));
            o0.y = __logf(A1 * bf2f(ee[1]) + A2 * ((rp0.y < SS) ? ev[rp0.y] : cc));
            o0.z = __logf(A1 * bf2f(ee[2]) + A2 * ((rp0.z < SS) ? ev[rp0.z] : cc));
            o0.w = __logf(A1 * bf2f(ee[3]) + A2 * ((rp0.w < SS) ? ev[rp0.w] : cc));
            o1.x = __logf(A1 * bf2f(ee[4]) + A2 * ((rp1.x < SS) ? ev[rp1.x] : cc));
            o1.y = __logf(A1 * bf2f(ee[5]) + A2 * ((rp1.y < SS) ? ev[rp1.y] : cc));
            o1.z = __logf(A1 * bf2f(ee[6]) + A2 * ((rp1.z < SS) ? ev[rp1.z] : cc));
            o1.w = __logf(A1 * bf2f(ee[7]) + A2 * ((rp1.w < SS) ? ev[rp1.w] : cc));
            row[2 * i] = o0;
            row[2 * i + 1] = o1;
        }
    } else {
        for (int i = tid; i < VV / 4; i += 256) {
            float4 g = row[i];
            int4 rp = pm[i];
            float4 o;
            o.x = __logf(A1 * __expf(g.x) + A2 * ((rp.x < SS) ? ev[rp.x] : cc));
            o.y = __logf(A1 * __expf(g.y) + A2 * ((rp.y < SS) ? ev[rp.y] : cc));
            o.z = __logf(A1 * __expf(g.z) + A2 * ((rp.z < SS) ? ev[rp.z] : cc));
            o.w = __logf(A1 * __expf(g.w) + A2 * ((rp.w < SS) ? ev[rp.w] : cc));
            row[i] = o;
        }
    }
}

extern "C" void kernel_launch(void* const* d_in, const int* in_sizes, int n_in,
                              void* d_out, int out_size, void* d_ws, size_t ws_size,
                              hipStream_t stream) {
    const int* src = (const int*)d_in[0];
    const float* dec = (const float*)d_in[1];
    const float* dattn = (const float*)d_in[2];
    const float* mem = (const float*)d_in[3];
    const float* wgen = (const float*)d_in[4];
    const float* bgen = (const float*)d_in[5];
    const float* wprob = (const float*)d_in[6];
    const float* bprob = (const float*)d_in[7];
    float* out = (float*)d_out;
    char* ws = (char*)d_ws;

    // ws layout
    int* pos_map = (int*)(ws + 0);                       // 1,024,000 B (pad 1 MB)
    float* e_vals = (float*)(ws + 1048576);              // 2 MB
    float* mw   = (float*)(ws + 3145728);                // 16 KB
    float* dw   = (float*)(ws + 3145728 + 16384);
    float* prob = (float*)(ws + 3145728 + 20480);
    float* zc   = (float*)(ws + 3145728 + 24576);
    float* c0   = (float*)(ws + 3145728 + 28672);
    float* zg   = (float*)(ws + 3145728 + 32768);
    unsigned short* Wbf = (unsigned short*)(ws + 3211264);              // 65,536,000 B
    unsigned short* Abf = (unsigned short*)(ws + 3211264 + 65536000);   // 2 MB
    unsigned short* Ebf = (unsigned short*)(ws + 3211264 + 65536000 + 2097152);  // 65,536,000 B
    const size_t NEEDED  = 3211264ull + 65536000ull + 2097152ull;
    const size_t NEEDED2 = NEEDED + 65536000ull;

    bool do_cast = ws_size >= NEEDED;

    k_pm_init<<<(BB * VV + 255) / 256, 256, 0, stream>>>(pos_map, zg);
    k_setup<<<do_cast ? 1192 : 648, 512, 0, stream>>>(
        src, pos_map, mem, dec, wprob, mw, dw, wgen,
        do_cast ? Wbf : nullptr, do_cast ? Abf : nullptr);
    k_row<<<MM, 256, 0, stream>>>(dattn, src, pos_map, mw, dw, bprob, e_vals, prob, zc, c0);

    if (do_cast) {
        if (ws_size >= NEEDED2) {
            k_gemm_bf<1><<<(MM / 128) * (VV / 256), 512, 0, stream>>>(Abf, Wbf, bgen, out, Ebf, zg);
            k_final<1><<<MM, 256, 0, stream>>>(out, Ebf, pos_map, e_vals, prob, zc, c0, zg);
        } else {
            k_gemm_bf<0><<<(MM / 128) * (VV / 256), 512, 0, stream>>>(Abf, Wbf, bgen, out, Ebf, zg);
            k_final<0><<<MM, 256, 0, stream>>>(out, Ebf, pos_map, e_vals, prob, zc, c0, zg);
        }
    } else {
        k_gemm_f32<<<(MM / FBb) * (VV / FBb), 256, 0, stream>>>(dec, wgen, bgen, out, zg);
        k_final<0><<<MM, 256, 0, stream>>>(out, Ebf, pos_map, e_vals, prob, zc, c0, zg);
    }
}

// Round 12
// 217.424 us; speedup vs baseline: 1.0355x; 1.0355x over previous
//
#include <hip/hip_runtime.h>
#include <hip/hip_bf16.h>
#include <cstddef>
#include <cstdint>

// Problem constants
#define BB 8
#define HH 16
#define TT 128
#define SS 512
#define DD 1024
#define VV 32000
#define MM (BB * TT)   // 1024 output rows

typedef float f32x4 __attribute__((ext_vector_type(4)));
typedef short short8v __attribute__((ext_vector_type(8)));
typedef unsigned short ushort8v __attribute__((ext_vector_type(8)));

__device__ __forceinline__ unsigned short f2bf(float x) {
    __hip_bfloat16 h = __float2bfloat16(x);
    return __builtin_bit_cast(unsigned short, h);
}
__device__ __forceinline__ float bf2f(unsigned short u) {
    unsigned int x = ((unsigned int)u) << 16;
    return __builtin_bit_cast(float, x);
}

__device__ __forceinline__ float wave_sum(float v) {
#pragma unroll
    for (int o = 1; o < 64; o <<= 1) v += __shfl_xor(v, o);
    return v;
}
__device__ __forceinline__ float wave_max(float v) {
#pragma unroll
    for (int o = 1; o < 64; o <<= 1) v = fmaxf(v, __shfl_xor(v, o));
    return v;
}
__device__ __forceinline__ float block_sum(float v, float* red, int tid) {
    v = wave_sum(v);
    __syncthreads();
    if ((tid & 63) == 0) red[tid >> 6] = v;
    __syncthreads();
    return red[0] + red[1] + red[2] + red[3];
}
__device__ __forceinline__ float block_max(float v, float* red, int tid) {
    v = wave_max(v);
    __syncthreads();
    if ((tid & 63) == 0) red[tid >> 6] = v;
    __syncthreads();
    return fmaxf(fmaxf(red[0], red[1]), fmaxf(red[2], red[3]));
}

// ---------------- merged setup: pm_build | vecdots | cast-W | cast-A ----------------
// Region layout (512-thread blocks):
//   [0,8)        pm_build           (8 x 512 tokens; pos_map pre-set to 0x7F7F7F7F)
//   [8,648)      vecdots, 8 rows/block (5120 rows)
//   [648,1672)   cast W_gen f32->bf16, grid-stride (1024 blocks)  [if do_cast]
//   [1672,1704)  cast dec  f32->bf16, grid-stride (32 blocks)     [if do_cast]
__global__ __launch_bounds__(512) void k_setup(const int* __restrict__ src,
                                               int* __restrict__ pos_map,
                                               const float* __restrict__ memory,
                                               const float* __restrict__ dec,
                                               const float* __restrict__ wprob,
                                               float* __restrict__ mw,
                                               float* __restrict__ dw,
                                               const float* __restrict__ wgen,
                                               unsigned short* __restrict__ Wbf,
                                               unsigned short* __restrict__ Abf) {
    int blk = blockIdx.x, tid = threadIdx.x;
    if (blk < 8) {
        int tok = src[blk * SS + tid];
        atomicMin(&pos_map[blk * VV + tok], tid);
    } else if (blk < 648) {
        int row = (blk - 8) * 8 + (tid >> 6);
        int lane = tid & 63;
        const float4* srcv;
        const float4* wv;
        if (row < BB * SS) {
            srcv = reinterpret_cast<const float4*>(memory + (size_t)row * DD);
            wv = reinterpret_cast<const float4*>(wprob);
        } else {
            srcv = reinterpret_cast<const float4*>(dec + (size_t)(row - BB * SS) * DD);
            wv = reinterpret_cast<const float4*>(wprob + DD);
        }
        float sum = 0.f;
#pragma unroll
        for (int k = 0; k < 4; ++k) {
            int idx = lane + 64 * k;
            float4 a = srcv[idx];
            float4 w = wv[idx];
            sum += a.x * w.x + a.y * w.y + a.z * w.z + a.w * w.w;
        }
        sum = wave_sum(sum);
        if (lane == 0) {
            if (row < BB * SS) mw[row] = sum;
            else dw[row - BB * SS] = sum;
        }
    } else if (blk < 1672) {
        if (Wbf == nullptr) return;
        const int n8 = VV * DD / 8;
        for (int i = (blk - 648) * 512 + tid; i < n8; i += 1024 * 512) {
            const float4* p = reinterpret_cast<const float4*>(wgen + (size_t)i * 8);
            float4 a = p[0], b = p[1];
            ushort8v u;
            u[0] = f2bf(a.x); u[1] = f2bf(a.y); u[2] = f2bf(a.z); u[3] = f2bf(a.w);
            u[4] = f2bf(b.x); u[5] = f2bf(b.y); u[6] = f2bf(b.z); u[7] = f2bf(b.w);
            *reinterpret_cast<ushort8v*>(Wbf + (size_t)i * 8) = u;
        }
    } else {
        if (Abf == nullptr) return;
        const int n8 = MM * DD / 8;
        for (int i = (blk - 1672) * 512 + tid; i < n8; i += 32 * 512) {
            const float4* p = reinterpret_cast<const float4*>(dec + (size_t)i * 8);
            float4 a = p[0], b = p[1];
            ushort8v u;
            u[0] = f2bf(a.x); u[1] = f2bf(a.y); u[2] = f2bf(a.z); u[3] = f2bf(a.w);
            u[4] = f2bf(b.x); u[5] = f2bf(b.y); u[6] = f2bf(b.z); u[7] = f2bf(b.w);
            *reinterpret_cast<ushort8v*>(Abf + (size_t)i * 8) = u;
        }
    }
}

// ---------------- per-(b,t) row: attn mean, scatter, prob, copy-Z ----------------
__global__ __launch_bounds__(256) void k_row(const float* __restrict__ dattn,
                                             const int* __restrict__ src,
                                             const int* __restrict__ pos_map,
                                             const float* __restrict__ mw,
                                             const float* __restrict__ dw,
                                             const float* __restrict__ bprob,
                                             float* __restrict__ e_vals,
                                             float* __restrict__ prob,
                                             float* __restrict__ zc,
                                             float* __restrict__ c0) {
    int bt = blockIdx.x;
    int b = bt >> 7;
    int t = bt & 127;
    int tid = threadIdx.x;
    __shared__ float a_row[SS];
    __shared__ float vals[SS];
    __shared__ int reps[SS];
    __shared__ float red[4];

    // head mean, float2-vectorized: thread tid owns elems {2tid, 2tid+1}
    {
        const float2* base = reinterpret_cast<const float2*>(
            dattn + ((size_t)b * HH * TT + t) * SS) + tid;
        float sx = 0.f, sy = 0.f;
#pragma unroll
        for (int h = 0; h < HH; ++h) {
            float2 v = base[(size_t)h * (TT * SS / 2)];
            sx += v.x; sy += v.y;
        }
        a_row[2 * tid] = sx * 0.0625f;
        a_row[2 * tid + 1] = sy * 0.0625f;
        vals[2 * tid] = 0.f;
        vals[2 * tid + 1] = 0.f;
    }
    // rep cache: one gather per s, reused by all later loops
    {
        int s0 = 2 * tid, s1 = 2 * tid + 1;
        reps[s0] = pos_map[b * VV + src[b * SS + s0]];
        reps[s1] = pos_map[b * VV + src[b * SS + s1]];
    }
    __syncthreads();
    for (int s = tid; s < SS; s += 256) {
        atomicAdd(&vals[reps[s]], a_row[s]);
    }
    __syncthreads();
    float psum = 0.f;
    for (int s = tid; s < SS; s += 256) psum += a_row[s] * mw[b * SS + s];
    psum = block_sum(psum, red, tid);
    float z = psum + dw[bt] + bprob[0];
    float p = 1.0f / (1.0f + __expf(-z));
    float mxv = -3.4e38f;
    for (int s = tid; s < SS; s += 256) {
        if (reps[s] == s) mxv = fmaxf(mxv, vals[s]);
    }
    mxv = block_max(mxv, red, tid);
    float m_c = fmaxf(0.0f, mxv);
    float sexp = 0.f, cnt = 0.f;
    for (int s = tid; s < SS; s += 256) {
        float e = 0.0f;
        if (reps[s] == s) {
            e = __expf(vals[s] - m_c);
            sexp += e;
            cnt += 1.0f;
        }
        e_vals[(size_t)bt * SS + s] = e;
    }
    sexp = block_sum(sexp, red, tid);
    cnt = block_sum(cnt, red, tid);
    if (tid == 0) {
        prob[bt] = p;
        zc[bt] = ((float)VV - cnt) * __expf(-m_c) + sexp;
        c0[bt] = __expf(-m_c);
    }
}

// =====================================================================
// 128x256 bf16 MFMA GEMM, 8 waves (64x64), BK=32, TRIPLE buffer, 2-deep
// prefetch, counted vmcnt(3). Conflict-free XOR swizzle (verified: 0
// conflicts). Settled structure: R8/R10/R11 all land 99-100 us; cycle
// accounting says the LDS-read pipe (~1900 cyc/iter/CU vs MFMA ~1030)
// plus barrier latency is the binding constraint for this tile family.
// =====================================================================
#define NKT 32          // K tiles = 1024/32
#define BUFE 12288      // elems per buffer: A 128*32=4096 + B 256*32=8192

#define AS1 __attribute__((address_space(1)))
#define AS3 __attribute__((address_space(3)))

template <int EPI>
__global__ __launch_bounds__(512, 4) void k_gemm_bf(const unsigned short* __restrict__ Abf,
                                                    const unsigned short* __restrict__ Wbf,
                                                    const float* __restrict__ bgen,
                                                    float* __restrict__ out,
                                                    unsigned short* __restrict__ ebuf,
                                                    float* __restrict__ zg) {
    __shared__ unsigned short lds[3 * BUFE];   // 72 KiB

    int tid = threadIdx.x;
    int p = blockIdx.x;
    // bijective XCD swizzle: 1000 = 8 * 125
    int wgid = (p & 7) * 125 + (p >> 3);
    int mt = wgid & 7, nt = wgid >> 3;   // consecutive wg share nt -> W L2 reuse
    int m0 = mt * 128, v0 = nt * 256;

    int lane = tid & 63, w = tid >> 6;
    int wm = w & 1, wn = w >> 1;         // wave owns 64(M) x 64(N)

    // staging: pre-swizzled source chunk ((tid&3)^((tid>>3)&3)), linear LDS dest
    int srow = tid >> 2;                 // 0..127
    int schunk = (tid & 3) ^ ((tid >> 3) & 3);
    const unsigned short* gA = Abf + (size_t)(m0 + srow) * DD + schunk * 8;
    const unsigned short* gB = Wbf + (size_t)(v0 + srow) * DD + schunk * 8;

    // per tile: 1 A-load + 2 B-loads per thread (vmcnt granularity = 3)
#define STAGE(T, BI) do {                                                              \
    size_t ko_ = (size_t)(T) * 32;                                                     \
    __builtin_amdgcn_global_load_lds(                                                  \
        (const AS1 void*)(gA + ko_),                                                   \
        (AS3 void*)(lds + (BI) * BUFE + tid * 8), 16, 0, 0);                           \
    __builtin_amdgcn_global_load_lds(                                                  \
        (const AS1 void*)(gB + ko_),                                                   \
        (AS3 void*)(lds + (BI) * BUFE + 4096 + tid * 8), 16, 0, 0);                    \
    __builtin_amdgcn_global_load_lds(                                                  \
        (const AS1 void*)(gB + (size_t)128 * DD + ko_),                                \
        (AS3 void*)(lds + (BI) * BUFE + 8192 + tid * 8), 16, 0, 0);                    \
} while (0)

    // fragment reads: row base multiple of 16 -> xr depends only on lr
    int lr = lane & 15, kg = lane >> 4;
    int xr = (lr >> 1) & 3;
    const unsigned short* arow = lds + (wm * 64 + lr) * 32 + ((kg ^ xr) << 3);
    const unsigned short* brow = lds + 4096 + (wn * 64 + lr) * 32 + ((kg ^ xr) << 3);

    f32x4 acc[4][4] = {};

#define ITER(T, BI, DO_STAGE, VM)  do {                                                \
    __builtin_amdgcn_s_barrier();                                                      \
    short8v af[4], bfr[4];                                                             \
    _Pragma("unroll")                                                                  \
    for (int i = 0; i < 4; ++i) {                                                      \
        af[i] = *reinterpret_cast<const short8v*>(arow + (BI) * BUFE + i * 512);       \
        bfr[i] = *reinterpret_cast<const short8v*>(brow + (BI) * BUFE + i * 512);      \
    }                                                                                  \
    if (DO_STAGE) STAGE((T) + 2, ((BI) + 2) % 3);                                      \
    __builtin_amdgcn_s_setprio(1);                                                     \
    _Pragma("unroll")                                                                  \
    for (int i = 0; i < 4; ++i)                                                        \
        _Pragma("unroll")                                                              \
        for (int j = 0; j < 4; ++j)                                                    \
            acc[i][j] = __builtin_amdgcn_mfma_f32_16x16x32_bf16(af[i], bfr[j], acc[i][j], 0, 0, 0); \
    __builtin_amdgcn_s_setprio(0);                                                     \
    if ((VM) == 3) asm volatile("s_waitcnt vmcnt(3)" ::: "memory");                    \
    else if ((VM) == 0) asm volatile("s_waitcnt vmcnt(0)" ::: "memory");               \
} while (0)

    // prologue: stage tiles 0,1; wait tile 0 (3 newest = tile 1 still in flight)
    STAGE(0, 0);
    STAGE(1, 1);
    asm volatile("s_waitcnt vmcnt(3)" ::: "memory");

    for (int t = 0; t < NKT - 2; t += 3) {
        ITER(t + 0, 0, true, 3);
        ITER(t + 1, 1, true, 3);
        ITER(t + 2, 2, true, 3);
    }
    ITER(30, 0, false, 0);
    ITER(31, 1, false, -1);
#undef ITER
#undef STAGE

    // ---- epilogue: bias + exp + store + per-row exp-sum atomics
    int colb = lane & 15, rgrp = lane >> 4;
#pragma unroll
    for (int i = 0; i < 4; ++i) {
        float es0 = 0.f, es1 = 0.f, es2 = 0.f, es3 = 0.f;
        int gmb = m0 + wm * 64 + i * 16 + rgrp * 4;
#pragma unroll
        for (int j = 0; j < 4; ++j) {
            int gv = v0 + wn * 64 + j * 16 + colb;
            float bgj = bgen[gv];
            float v0f = acc[i][j][0] + bgj;
            float v1f = acc[i][j][1] + bgj;
            float v2f = acc[i][j][2] + bgj;
            float v3f = acc[i][j][3] + bgj;
            float e0 = __expf(v0f), e1 = __expf(v1f), e2 = __expf(v2f), e3 = __expf(v3f);
            if constexpr (EPI == 1) {
                ebuf[(size_t)(gmb + 0) * VV + gv] = f2bf(e0);
                ebuf[(size_t)(gmb + 1) * VV + gv] = f2bf(e1);
                ebuf[(size_t)(gmb + 2) * VV + gv] = f2bf(e2);
                ebuf[(size_t)(gmb + 3) * VV + gv] = f2bf(e3);
            } else {
                out[(size_t)(gmb + 0) * VV + gv] = v0f;
                out[(size_t)(gmb + 1) * VV + gv] = v1f;
                out[(size_t)(gmb + 2) * VV + gv] = v2f;
                out[(size_t)(gmb + 3) * VV + gv] = v3f;
            }
            es0 += e0; es1 += e1; es2 += e2; es3 += e3;
        }
        float es[4] = {es0, es1, es2, es3};
#pragma unroll
        for (int rr = 0; rr < 4; ++rr) {
            float e = es[rr];
            e += __shfl_xor(e, 1); e += __shfl_xor(e, 2);
            e += __shfl_xor(e, 4); e += __shfl_xor(e, 8);
            if (colb == 0) atomicAdd(&zg[gmb + rr], e);
        }
    }
}

// ---------------- fallback GEMM (f32 inputs, in-register cast, 128^2) ----------------
#define FBb 128
#define FLDK 40

__global__ __launch_bounds__(256) void k_gemm_f32(const float* __restrict__ A,
                                                  const float* __restrict__ Wg,
                                                  const float* __restrict__ bgen,
                                                  float* __restrict__ out,
                                                  float* __restrict__ zg) {
    __shared__ unsigned short As[FBb * FLDK];
    __shared__ unsigned short Bs[FBb * FLDK];
    int tid = threadIdx.x;
    int bid = blockIdx.x;
    int mt = bid & 7;
    int nt = bid >> 3;
    int m0 = mt * FBb, v0 = nt * FBb;
    int lane = tid & 63, wid = tid >> 6;
    int wr = (wid >> 1) * 64, wc = (wid & 1) * 64;
    int lr = lane & 15, lk = (lane >> 4) << 3;
    int r = tid >> 1, c0 = (tid & 1) << 4;

    f32x4 acc[4][4] = {};

    for (int k0 = 0; k0 < DD; k0 += 32) {
        {
            const float4* pa = reinterpret_cast<const float4*>(A + (size_t)(m0 + r) * DD + k0 + c0);
            float4 x0 = pa[0], x1 = pa[1], x2 = pa[2], x3 = pa[3];
            ushort8v u0, u1;
            u0[0] = f2bf(x0.x); u0[1] = f2bf(x0.y); u0[2] = f2bf(x0.z); u0[3] = f2bf(x0.w);
            u0[4] = f2bf(x1.x); u0[5] = f2bf(x1.y); u0[6] = f2bf(x1.z); u0[7] = f2bf(x1.w);
            u1[0] = f2bf(x2.x); u1[1] = f2bf(x2.y); u1[2] = f2bf(x2.z); u1[3] = f2bf(x2.w);
            u1[4] = f2bf(x3.x); u1[5] = f2bf(x3.y); u1[6] = f2bf(x3.z); u1[7] = f2bf(x3.w);
            *reinterpret_cast<ushort8v*>(&As[r * FLDK + c0]) = u0;
            *reinterpret_cast<ushort8v*>(&As[r * FLDK + c0 + 8]) = u1;

            const float4* pb = reinterpret_cast<const float4*>(Wg + (size_t)(v0 + r) * DD + k0 + c0);
            float4 y0 = pb[0], y1 = pb[1], y2 = pb[2], y3 = pb[3];
            ushort8v w0, w1;
            w0[0] = f2bf(y0.x); w0[1] = f2bf(y0.y); w0[2] = f2bf(y0.z); w0[3] = f2bf(y0.w);
            w0[4] = f2bf(y1.x); w0[5] = f2bf(y1.y); w0[6] = f2bf(y1.z); w0[7] = f2bf(y1.w);
            w1[0] = f2bf(y2.x); w1[1] = f2bf(y2.y); w1[2] = f2bf(y2.z); w1[3] = f2bf(y2.w);
            w1[4] = f2bf(y3.x); w1[5] = f2bf(y3.y); w1[6] = f2bf(y3.z); w1[7] = f2bf(y3.w);
            *reinterpret_cast<ushort8v*>(&Bs[r * FLDK + c0]) = w0;
            *reinterpret_cast<ushort8v*>(&Bs[r * FLDK + c0 + 8]) = w1;
        }
        __syncthreads();

        short8v af[4], bfr[4];
#pragma unroll
        for (int i = 0; i < 4; ++i)
            af[i] = *reinterpret_cast<const short8v*>(&As[(wr + i * 16 + lr) * FLDK + lk]);
#pragma unroll
        for (int j = 0; j < 4; ++j)
            bfr[j] = *reinterpret_cast<const short8v*>(&Bs[(wc + j * 16 + lr) * FLDK + lk]);
#pragma unroll
        for (int i = 0; i < 4; ++i)
#pragma unroll
            for (int j = 0; j < 4; ++j)
                acc[i][j] = __builtin_amdgcn_mfma_f32_16x16x32_bf16(af[i], bfr[j], acc[i][j], 0, 0, 0);
        __syncthreads();
    }

    int colb = lane & 15;
    int rgrp = lane >> 4;
#pragma unroll
    for (int i = 0; i < 4; ++i) {
        float es0 = 0.f, es1 = 0.f, es2 = 0.f, es3 = 0.f;
        int gmb = m0 + wr + i * 16 + rgrp * 4;
#pragma unroll
        for (int j = 0; j < 4; ++j) {
            int gv = v0 + wc + j * 16 + colb;
            float bgj = bgen[gv];
            float v0f = acc[i][j][0] + bgj;
            float v1f = acc[i][j][1] + bgj;
            float v2f = acc[i][j][2] + bgj;
            float v3f = acc[i][j][3] + bgj;
            out[(size_t)(gmb + 0) * VV + gv] = v0f;
            out[(size_t)(gmb + 1) * VV + gv] = v1f;
            out[(size_t)(gmb + 2) * VV + gv] = v2f;
            out[(size_t)(gmb + 3) * VV + gv] = v3f;
            es0 += __expf(v0f); es1 += __expf(v1f);
            es2 += __expf(v2f); es3 += __expf(v3f);
        }
        float es[4] = {es0, es1, es2, es3};
#pragma unroll
        for (int rr = 0; rr < 4; ++rr) {
            float e = es[rr];
            e += __shfl_xor(e, 1); e += __shfl_xor(e, 2);
            e += __shfl_xor(e, 4); e += __shfl_xor(e, 8);
            if (colb == 0) atomicAdd(&zg[gmb + rr], e);
        }
    }
}

// ---------------- final combine into d_out ----------------
template <int RD16>
__global__ __launch_bounds__(256) void k_final(float* __restrict__ gen,
                                               const unsigned short* __restrict__ ebuf,
                                               const int* __restrict__ pos_map,
                                               const float* __restrict__ e_vals,
                                               const float* __restrict__ prob,
                                               const float* __restrict__ zc,
                                               const float* __restrict__ c0,
                                               const float* __restrict__ zg) {
    int m = blockIdx.x;
    int b = m >> 7;
    int tid = threadIdx.x;
    float p = prob[m];
    float A1 = p / zg[m];
    float A2 = (1.0f - p) / zc[m];
    float cc = c0[m];
    const float* ev = e_vals + (size_t)m * SS;
    float4* row = reinterpret_cast<float4*>(gen + (size_t)m * VV);
    const int4* pm = reinterpret_cast<const int4*>(pos_map + b * VV);
    if constexpr (RD16 == 1) {
        const ushort8v* erow = reinterpret_cast<const ushort8v*>(ebuf + (size_t)m * VV);
        for (int i = tid; i < VV / 8; i += 256) {
            ushort8v ee = erow[i];
            int4 rp0 = pm[2 * i], rp1 = pm[2 * i + 1];
            float4 o0, o1;
            o0.x = __logf(A1 * bf2f(ee[0]) + A2 * ((rp0.x < SS) ? ev[rp0.x] : cc));
            o0.y = __logf(A1 * bf2f(ee[1]) + A2 * ((rp0.y < SS) ? ev[rp0.y] : cc));
            o0.z = __logf(A1 * bf2f(ee[2]) + A2 * ((rp0.z < SS) ? ev[rp0.z] : cc));
            o0.w = __logf(A1 * bf2f(ee[3]) + A2 * ((rp0.w < SS) ? ev[rp0.w] : cc));
            o1.x = __logf(A1 * bf2f(ee[4]) + A2 * ((rp1.x < SS) ? ev[rp1.x] : cc));
            o1.y = __logf(A1 * bf2f(ee[5]) + A2 * ((rp1.y < SS) ? ev[rp1.y] : cc));
            o1.z = __logf(A1 * bf2f(ee[6]) + A2 * ((rp1.z < SS) ? ev[rp1.z] : cc));
            o1.w = __logf(A1 * bf2f(ee[7]) + A2 * ((rp1.w < SS) ? ev[rp1.w] : cc));
            row[2 * i] = o0;
            row[2 * i + 1] = o1;
        }
    } else {
        for (int i = tid; i < VV / 4; i += 256) {
            float4 g = row[i];
            int4 rp = pm[i];
            float4 o;
            o.x = __logf(A1 * __expf(g.x) + A2 * ((rp.x < SS) ? ev[rp.x] : cc));
            o.y = __logf(A1 * __expf(g.y) + A2 * ((rp.y < SS) ? ev[rp.y] : cc));
            o.z = __logf(A1 * __expf(g.z) + A2 * ((rp.z < SS) ? ev[rp.z] : cc));
            o.w = __logf(A1 * __expf(g.w) + A2 * ((rp.w < SS) ? ev[rp.w] : cc));
            row[i] = o;
        }
    }
}

extern "C" void kernel_launch(void* const* d_in, const int* in_sizes, int n_in,
                              void* d_out, int out_size, void* d_ws, size_t ws_size,
                              hipStream_t stream) {
    const int* src = (const int*)d_in[0];
    const float* dec = (const float*)d_in[1];
    const float* dattn = (const float*)d_in[2];
    const float* mem = (const float*)d_in[3];
    const float* wgen = (const float*)d_in[4];
    const float* bgen = (const float*)d_in[5];
    const float* wprob = (const float*)d_in[6];
    const float* bprob = (const float*)d_in[7];
    float* out = (float*)d_out;
    char* ws = (char*)d_ws;

    // ws layout
    int* pos_map = (int*)(ws + 0);                       // 1,024,000 B (pad 1 MB)
    float* e_vals = (float*)(ws + 1048576);              // 2 MB
    float* mw   = (float*)(ws + 3145728);                // 16 KB
    float* dw   = (float*)(ws + 3145728 + 16384);
    float* prob = (float*)(ws + 3145728 + 20480);
    float* zc   = (float*)(ws + 3145728 + 24576);
    float* c0   = (float*)(ws + 3145728 + 28672);
    float* zg   = (float*)(ws + 3145728 + 32768);
    unsigned short* Wbf = (unsigned short*)(ws + 3211264);              // 65,536,000 B
    unsigned short* Abf = (unsigned short*)(ws + 3211264 + 65536000);   // 2 MB
    unsigned short* Ebf = (unsigned short*)(ws + 3211264 + 65536000 + 2097152);  // 65,536,000 B
    const size_t NEEDED  = 3211264ull + 65536000ull + 2097152ull;
    const size_t NEEDED2 = NEEDED + 65536000ull;

    bool do_cast = ws_size >= NEEDED;

    // pos_map "infinity" = 0x7F7F7F7F (> any s in [0,512)); zg = 0.0f
    hipMemsetAsync(pos_map, 0x7F, (size_t)BB * VV * sizeof(int), stream);
    hipMemsetAsync(zg, 0, (size_t)MM * sizeof(float), stream);

    k_setup<<<do_cast ? 1704 : 648, 512, 0, stream>>>(
        src, pos_map, mem, dec, wprob, mw, dw, wgen,
        do_cast ? Wbf : nullptr, do_cast ? Abf : nullptr);
    k_row<<<MM, 256, 0, stream>>>(dattn, src, pos_map, mw, dw, bprob, e_vals, prob, zc, c0);

    if (do_cast) {
        if (ws_size >= NEEDED2) {
            k_gemm_bf<1><<<(MM / 128) * (VV / 256), 512, 0, stream>>>(Abf, Wbf, bgen, out, Ebf, zg);
            k_final<1><<<MM, 256, 0, stream>>>(out, Ebf, pos_map, e_vals, prob, zc, c0, zg);
        } else {
            k_gemm_bf<0><<<(MM / 128) * (VV / 256), 512, 0, stream>>>(Abf, Wbf, bgen, out, Ebf, zg);
            k_final<0><<<MM, 256, 0, stream>>>(out, Ebf, pos_map, e_vals, prob, zc, c0, zg);
        }
    } else {
        k_gemm_f32<<<(MM / FBb) * (VV / FBb), 256, 0, stream>>>(dec, wgen, bgen, out, zg);
        k_final<0><<<MM, 256, 0, stream>>>(out, Ebf, pos_map, e_vals, prob, zc, c0, zg);
    }
}

// Round 13
// 215.158 us; speedup vs baseline: 1.0464x; 1.0105x over previous
//
#include <hip/hip_runtime.h>
#include <hip/hip_bf16.h>
#include <cstddef>
#include <cstdint>

// Problem constants
#define BB 8
#define HH 16
#define TT 128
#define SS 512
#define DD 1024
#define VV 32000
#define MM (BB * TT)   // 1024 output rows

typedef float f32x4 __attribute__((ext_vector_type(4)));
typedef short short8v __attribute__((ext_vector_type(8)));
typedef unsigned short ushort8v __attribute__((ext_vector_type(8)));

__device__ __forceinline__ unsigned short f2bf(float x) {
    __hip_bfloat16 h = __float2bfloat16(x);
    return __builtin_bit_cast(unsigned short, h);
}
__device__ __forceinline__ float bf2f(unsigned short u) {
    unsigned int x = ((unsigned int)u) << 16;
    return __builtin_bit_cast(float, x);
}

__device__ __forceinline__ float wave_sum(float v) {
#pragma unroll
    for (int o = 1; o < 64; o <<= 1) v += __shfl_xor(v, o);
    return v;
}
__device__ __forceinline__ float wave_max(float v) {
#pragma unroll
    for (int o = 1; o < 64; o <<= 1) v = fmaxf(v, __shfl_xor(v, o));
    return v;
}
__device__ __forceinline__ float block_sum(float v, float* red, int tid) {
    v = wave_sum(v);
    __syncthreads();
    if ((tid & 63) == 0) red[tid >> 6] = v;
    __syncthreads();
    return red[0] + red[1] + red[2] + red[3];
}
__device__ __forceinline__ float block_max(float v, float* red, int tid) {
    v = wave_max(v);
    __syncthreads();
    if ((tid & 63) == 0) red[tid >> 6] = v;
    __syncthreads();
    return fmaxf(fmaxf(red[0], red[1]), fmaxf(red[2], red[3]));
}

// ---------------- setup1: pm_build | vecdots | cast-A ----------------
// 512-thread blocks: [0,8) pm_build; [8,648) vecdots (8 rows/blk);
// [648,680) cast dec f32->bf16 (grid-stride). All k_row prerequisites.
__global__ __launch_bounds__(512) void k_setup1(const int* __restrict__ src,
                                                int* __restrict__ pos_map,
                                                const float* __restrict__ memory,
                                                const float* __restrict__ dec,
                                                const float* __restrict__ wprob,
                                                float* __restrict__ mw,
                                                float* __restrict__ dw,
                                                unsigned short* __restrict__ Abf) {
    int blk = blockIdx.x, tid = threadIdx.x;
    if (blk < 8) {
        int tok = src[blk * SS + tid];
        atomicMin(&pos_map[blk * VV + tok], tid);
    } else if (blk < 648) {
        int row = (blk - 8) * 8 + (tid >> 6);
        int lane = tid & 63;
        const float4* srcv;
        const float4* wv;
        if (row < BB * SS) {
            srcv = reinterpret_cast<const float4*>(memory + (size_t)row * DD);
            wv = reinterpret_cast<const float4*>(wprob);
        } else {
            srcv = reinterpret_cast<const float4*>(dec + (size_t)(row - BB * SS) * DD);
            wv = reinterpret_cast<const float4*>(wprob + DD);
        }
        float sum = 0.f;
#pragma unroll
        for (int k = 0; k < 4; ++k) {
            int idx = lane + 64 * k;
            float4 a = srcv[idx];
            float4 w = wv[idx];
            sum += a.x * w.x + a.y * w.y + a.z * w.z + a.w * w.w;
        }
        sum = wave_sum(sum);
        if (lane == 0) {
            if (row < BB * SS) mw[row] = sum;
            else dw[row - BB * SS] = sum;
        }
    } else {
        if (Abf == nullptr) return;
        const int n8 = MM * DD / 8;
        for (int i = (blk - 648) * 512 + tid; i < n8; i += 32 * 512) {
            const float4* p = reinterpret_cast<const float4*>(dec + (size_t)i * 8);
            float4 a = p[0], b = p[1];
            ushort8v u;
            u[0] = f2bf(a.x); u[1] = f2bf(a.y); u[2] = f2bf(a.z); u[3] = f2bf(a.w);
            u[4] = f2bf(b.x); u[5] = f2bf(b.y); u[6] = f2bf(b.z); u[7] = f2bf(b.w);
            *reinterpret_cast<ushort8v*>(Abf + (size_t)i * 8) = u;
        }
    }
}

// ---------------- rowcast: k_row (1024 blks) || cast-W (2048 blks) ----------------
// 256-thread blocks. The two regions are INDEPENDENT: k_row feeds k_final,
// cast-W feeds the GEMM. Co-scheduling them overlaps k_row's latency-bound
// gather work with the BW-bound W cast instead of serializing two kernels.
__global__ __launch_bounds__(256) void k_rowcast(const float* __restrict__ dattn,
                                                 const int* __restrict__ src,
                                                 const int* __restrict__ pos_map,
                                                 const float* __restrict__ mw,
                                                 const float* __restrict__ dw,
                                                 const float* __restrict__ bprob,
                                                 float* __restrict__ e_vals,
                                                 float* __restrict__ prob,
                                                 float* __restrict__ zc,
                                                 float* __restrict__ c0,
                                                 const float* __restrict__ wgen,
                                                 unsigned short* __restrict__ Wbf) {
    int blk = blockIdx.x, tid = threadIdx.x;
    if (blk >= MM) {
        // ---- cast-W region ----
        if (Wbf == nullptr) return;
        const int n8 = VV * DD / 8;
        for (int i = (blk - MM) * 256 + tid; i < n8; i += 2048 * 256) {
            const float4* p = reinterpret_cast<const float4*>(wgen + (size_t)i * 8);
            float4 a = p[0], b = p[1];
            ushort8v u;
            u[0] = f2bf(a.x); u[1] = f2bf(a.y); u[2] = f2bf(a.z); u[3] = f2bf(a.w);
            u[4] = f2bf(b.x); u[5] = f2bf(b.y); u[6] = f2bf(b.z); u[7] = f2bf(b.w);
            *reinterpret_cast<ushort8v*>(Wbf + (size_t)i * 8) = u;
        }
        return;
    }
    // ---- k_row region ----
    int bt = blk;
    int b = bt >> 7;
    int t = bt & 127;
    __shared__ float a_row[SS];
    __shared__ float vals[SS];
    __shared__ int reps[SS];
    __shared__ float red[4];

    {
        const float2* base = reinterpret_cast<const float2*>(
            dattn + ((size_t)b * HH * TT + t) * SS) + tid;
        float sx = 0.f, sy = 0.f;
#pragma unroll
        for (int h = 0; h < HH; ++h) {
            float2 v = base[(size_t)h * (TT * SS / 2)];
            sx += v.x; sy += v.y;
        }
        a_row[2 * tid] = sx * 0.0625f;
        a_row[2 * tid + 1] = sy * 0.0625f;
        vals[2 * tid] = 0.f;
        vals[2 * tid + 1] = 0.f;
    }
    {
        int s0 = 2 * tid, s1 = 2 * tid + 1;
        reps[s0] = pos_map[b * VV + src[b * SS + s0]];
        reps[s1] = pos_map[b * VV + src[b * SS + s1]];
    }
    __syncthreads();
    for (int s = tid; s < SS; s += 256) {
        atomicAdd(&vals[reps[s]], a_row[s]);
    }
    __syncthreads();
    float psum = 0.f;
    for (int s = tid; s < SS; s += 256) psum += a_row[s] * mw[b * SS + s];
    psum = block_sum(psum, red, tid);
    float z = psum + dw[bt] + bprob[0];
    float p = 1.0f / (1.0f + __expf(-z));
    float mxv = -3.4e38f;
    for (int s = tid; s < SS; s += 256) {
        if (reps[s] == s) mxv = fmaxf(mxv, vals[s]);
    }
    mxv = block_max(mxv, red, tid);
    float m_c = fmaxf(0.0f, mxv);
    float sexp = 0.f, cnt = 0.f;
    for (int s = tid; s < SS; s += 256) {
        float e = 0.0f;
        if (reps[s] == s) {
            e = __expf(vals[s] - m_c);
            sexp += e;
            cnt += 1.0f;
        }
        e_vals[(size_t)bt * SS + s] = e;
    }
    sexp = block_sum(sexp, red, tid);
    cnt = block_sum(cnt, red, tid);
    if (tid == 0) {
        prob[bt] = p;
        zc[bt] = ((float)VV - cnt) * __expf(-m_c) + sexp;
        c0[bt] = __expf(-m_c);
    }
}

// =====================================================================
// 128x256 bf16 MFMA GEMM, 8 waves (64x64), BK=32, TRIPLE buffer, 2-deep
// prefetch, counted vmcnt(3). Conflict-free XOR swizzle (verified: 0
// conflicts). Settled structure: R8/R10/R11/R12 all land 98-100 us.
// =====================================================================
#define NKT 32          // K tiles = 1024/32
#define BUFE 12288      // elems per buffer: A 128*32=4096 + B 256*32=8192

#define AS1 __attribute__((address_space(1)))
#define AS3 __attribute__((address_space(3)))

template <int EPI>
__global__ __launch_bounds__(512, 4) void k_gemm_bf(const unsigned short* __restrict__ Abf,
                                                    const unsigned short* __restrict__ Wbf,
                                                    const float* __restrict__ bgen,
                                                    float* __restrict__ out,
                                                    unsigned short* __restrict__ ebuf,
                                                    float* __restrict__ zg) {
    __shared__ unsigned short lds[3 * BUFE];   // 72 KiB

    int tid = threadIdx.x;
    int p = blockIdx.x;
    // bijective XCD swizzle: 1000 = 8 * 125
    int wgid = (p & 7) * 125 + (p >> 3);
    int mt = wgid & 7, nt = wgid >> 3;   // consecutive wg share nt -> W L2 reuse
    int m0 = mt * 128, v0 = nt * 256;

    int lane = tid & 63, w = tid >> 6;
    int wm = w & 1, wn = w >> 1;         // wave owns 64(M) x 64(N)

    // staging: pre-swizzled source chunk ((tid&3)^((tid>>3)&3)), linear LDS dest
    int srow = tid >> 2;                 // 0..127
    int schunk = (tid & 3) ^ ((tid >> 3) & 3);
    const unsigned short* gA = Abf + (size_t)(m0 + srow) * DD + schunk * 8;
    const unsigned short* gB = Wbf + (size_t)(v0 + srow) * DD + schunk * 8;

    // per tile: 1 A-load + 2 B-loads per thread (vmcnt granularity = 3)
#define STAGE(T, BI) do {                                                              \
    size_t ko_ = (size_t)(T) * 32;                                                     \
    __builtin_amdgcn_global_load_lds(                                                  \
        (const AS1 void*)(gA + ko_),                                                   \
        (AS3 void*)(lds + (BI) * BUFE + tid * 8), 16, 0, 0);                           \
    __builtin_amdgcn_global_load_lds(                                                  \
        (const AS1 void*)(gB + ko_),                                                   \
        (AS3 void*)(lds + (BI) * BUFE + 4096 + tid * 8), 16, 0, 0);                    \
    __builtin_amdgcn_global_load_lds(                                                  \
        (const AS1 void*)(gB + (size_t)128 * DD + ko_),                                \
        (AS3 void*)(lds + (BI) * BUFE + 8192 + tid * 8), 16, 0, 0);                    \
} while (0)

    // fragment reads: row base multiple of 16 -> xr depends only on lr
    int lr = lane & 15, kg = lane >> 4;
    int xr = (lr >> 1) & 3;
    const unsigned short* arow = lds + (wm * 64 + lr) * 32 + ((kg ^ xr) << 3);
    const unsigned short* brow = lds + 4096 + (wn * 64 + lr) * 32 + ((kg ^ xr) << 3);

    f32x4 acc[4][4] = {};

#define ITER(T, BI, DO_STAGE, VM)  do {                                                \
    __builtin_amdgcn_s_barrier();                                                      \
    short8v af[4], bfr[4];                                                             \
    _Pragma("unroll")                                                                  \
    for (int i = 0; i < 4; ++i) {                                                      \
        af[i] = *reinterpret_cast<const short8v*>(arow + (BI) * BUFE + i * 512);       \
        bfr[i] = *reinterpret_cast<const short8v*>(brow + (BI) * BUFE + i * 512);      \
    }                                                                                  \
    if (DO_STAGE) STAGE((T) + 2, ((BI) + 2) % 3);                                      \
    __builtin_amdgcn_s_setprio(1);                                                     \
    _Pragma("unroll")                                                                  \
    for (int i = 0; i < 4; ++i)                                                        \
        _Pragma("unroll")                                                              \
        for (int j = 0; j < 4; ++j)                                                    \
            acc[i][j] = __builtin_amdgcn_mfma_f32_16x16x32_bf16(af[i], bfr[j], acc[i][j], 0, 0, 0); \
    __builtin_amdgcn_s_setprio(0);                                                     \
    if ((VM) == 3) asm volatile("s_waitcnt vmcnt(3)" ::: "memory");                    \
    else if ((VM) == 0) asm volatile("s_waitcnt vmcnt(0)" ::: "memory");               \
} while (0)

    // prologue: stage tiles 0,1; wait tile 0 (3 newest = tile 1 still in flight)
    STAGE(0, 0);
    STAGE(1, 1);
    asm volatile("s_waitcnt vmcnt(3)" ::: "memory");

    for (int t = 0; t < NKT - 2; t += 3) {
        ITER(t + 0, 0, true, 3);
        ITER(t + 1, 1, true, 3);
        ITER(t + 2, 2, true, 3);
    }
    ITER(30, 0, false, 0);
    ITER(31, 1, false, -1);
#undef ITER
#undef STAGE

    // ---- epilogue: bias + exp + store + per-row exp-sum atomics
    int colb = lane & 15, rgrp = lane >> 4;
#pragma unroll
    for (int i = 0; i < 4; ++i) {
        float es0 = 0.f, es1 = 0.f, es2 = 0.f, es3 = 0.f;
        int gmb = m0 + wm * 64 + i * 16 + rgrp * 4;
#pragma unroll
        for (int j = 0; j < 4; ++j) {
            int gv = v0 + wn * 64 + j * 16 + colb;
            float bgj = bgen[gv];
            float v0f = acc[i][j][0] + bgj;
            float v1f = acc[i][j][1] + bgj;
            float v2f = acc[i][j][2] + bgj;
            float v3f = acc[i][j][3] + bgj;
            float e0 = __expf(v0f), e1 = __expf(v1f), e2 = __expf(v2f), e3 = __expf(v3f);
            if constexpr (EPI == 1) {
                ebuf[(size_t)(gmb + 0) * VV + gv] = f2bf(e0);
                ebuf[(size_t)(gmb + 1) * VV + gv] = f2bf(e1);
                ebuf[(size_t)(gmb + 2) * VV + gv] = f2bf(e2);
                ebuf[(size_t)(gmb + 3) * VV + gv] = f2bf(e3);
            } else {
                out[(size_t)(gmb + 0) * VV + gv] = v0f;
                out[(size_t)(gmb + 1) * VV + gv] = v1f;
                out[(size_t)(gmb + 2) * VV + gv] = v2f;
                out[(size_t)(gmb + 3) * VV + gv] = v3f;
            }
            es0 += e0; es1 += e1; es2 += e2; es3 += e3;
        }
        float es[4] = {es0, es1, es2, es3};
#pragma unroll
        for (int rr = 0; rr < 4; ++rr) {
            float e = es[rr];
            e += __shfl_xor(e, 1); e += __shfl_xor(e, 2);
            e += __shfl_xor(e, 4); e += __shfl_xor(e, 8);
            if (colb == 0) atomicAdd(&zg[gmb + rr], e);
        }
    }
}

// ---------------- fallback GEMM (f32 inputs, in-register cast, 128^2) ----------------
#define FBb 128
#define FLDK 40

__global__ __launch_bounds__(256) void k_gemm_f32(const float* __restrict__ A,
                                                  const float* __restrict__ Wg,
                                                  const float* __restrict__ bgen,
                                                  float* __restrict__ out,
                                                  float* __restrict__ zg) {
    __shared__ unsigned short As[FBb * FLDK];
    __shared__ unsigned short Bs[FBb * FLDK];
    int tid = threadIdx.x;
    int bid = blockIdx.x;
    int mt = bid & 7;
    int nt = bid >> 3;
    int m0 = mt * FBb, v0 = nt * FBb;
    int lane = tid & 63, wid = tid >> 6;
    int wr = (wid >> 1) * 64, wc = (wid & 1) * 64;
    int lr = lane & 15, lk = (lane >> 4) << 3;
    int r = tid >> 1, c0 = (tid & 1) << 4;

    f32x4 acc[4][4] = {};

    for (int k0 = 0; k0 < DD; k0 += 32) {
        {
            const float4* pa = reinterpret_cast<const float4*>(A + (size_t)(m0 + r) * DD + k0 + c0);
            float4 x0 = pa[0], x1 = pa[1], x2 = pa[2], x3 = pa[3];
            ushort8v u0, u1;
            u0[0] = f2bf(x0.x); u0[1] = f2bf(x0.y); u0[2] = f2bf(x0.z); u0[3] = f2bf(x0.w);
            u0[4] = f2bf(x1.x); u0[5] = f2bf(x1.y); u0[6] = f2bf(x1.z); u0[7] = f2bf(x1.w);
            u1[0] = f2bf(x2.x); u1[1] = f2bf(x2.y); u1[2] = f2bf(x2.z); u1[3] = f2bf(x2.w);
            u1[4] = f2bf(x3.x); u1[5] = f2bf(x3.y); u1[6] = f2bf(x3.z); u1[7] = f2bf(x3.w);
            *reinterpret_cast<ushort8v*>(&As[r * FLDK + c0]) = u0;
            *reinterpret_cast<ushort8v*>(&As[r * FLDK + c0 + 8]) = u1;

            const float4* pb = reinterpret_cast<const float4*>(Wg + (size_t)(v0 + r) * DD + k0 + c0);
            float4 y0 = pb[0], y1 = pb[1], y2 = pb[2], y3 = pb[3];
            ushort8v w0, w1;
            w0[0] = f2bf(y0.x); w0[1] = f2bf(y0.y); w0[2] = f2bf(y0.z); w0[3] = f2bf(y0.w);
            w0[4] = f2bf(y1.x); w0[5] = f2bf(y1.y); w0[6] = f2bf(y1.z); w0[7] = f2bf(y1.w);
            w1[0] = f2bf(y2.x); w1[1] = f2bf(y2.y); w1[2] = f2bf(y2.z); w1[3] = f2bf(y2.w);
            w1[4] = f2bf(y3.x); w1[5] = f2bf(y3.y); w1[6] = f2bf(y3.z); w1[7] = f2bf(y3.w);
            *reinterpret_cast<ushort8v*>(&Bs[r * FLDK + c0]) = w0;
            *reinterpret_cast<ushort8v*>(&Bs[r * FLDK + c0 + 8]) = w1;
        }
        __syncthreads();

        short8v af[4], bfr[4];
#pragma unroll
        for (int i = 0; i < 4; ++i)
            af[i] = *reinterpret_cast<const short8v*>(&As[(wr + i * 16 + lr) * FLDK + lk]);
#pragma unroll
        for (int j = 0; j < 4; ++j)
            bfr[j] = *reinterpret_cast<const short8v*>(&Bs[(wc + j * 16 + lr) * FLDK + lk]);
#pragma unroll
        for (int i = 0; i < 4; ++i)
#pragma unroll
            for (int j = 0; j < 4; ++j)
                acc[i][j] = __builtin_amdgcn_mfma_f32_16x16x32_bf16(af[i], bfr[j], acc[i][j], 0, 0, 0);
        __syncthreads();
    }

    int colb = lane & 15;
    int rgrp = lane >> 4;
#pragma unroll
    for (int i = 0; i < 4; ++i) {
        float es0 = 0.f, es1 = 0.f, es2 = 0.f, es3 = 0.f;
        int gmb = m0 + wr + i * 16 + rgrp * 4;
#pragma unroll
        for (int j = 0; j < 4; ++j) {
            int gv = v0 + wc + j * 16 + colb;
            float bgj = bgen[gv];
            float v0f = acc[i][j][0] + bgj;
            float v1f = acc[i][j][1] + bgj;
            float v2f = acc[i][j][2] + bgj;
            float v3f = acc[i][j][3] + bgj;
            out[(size_t)(gmb + 0) * VV + gv] = v0f;
            out[(size_t)(gmb + 1) * VV + gv] = v1f;
            out[(size_t)(gmb + 2) * VV + gv] = v2f;
            out[(size_t)(gmb + 3) * VV + gv] = v3f;
            es0 += __expf(v0f); es1 += __expf(v1f);
            es2 += __expf(v2f); es3 += __expf(v3f);
        }
        float es[4] = {es0, es1, es2, es3};
#pragma unroll
        for (int rr = 0; rr < 4; ++rr) {
            float e = es[rr];
            e += __shfl_xor(e, 1); e += __shfl_xor(e, 2);
            e += __shfl_xor(e, 4); e += __shfl_xor(e, 8);
            if (colb == 0) atomicAdd(&zg[gmb + rr], e);
        }
    }
}

// ---------------- final combine into d_out ----------------
template <int RD16>
__global__ __launch_bounds__(256) void k_final(float* __restrict__ gen,
                                               const unsigned short* __restrict__ ebuf,
                                               const int* __restrict__ pos_map,
                                               const float* __restrict__ e_vals,
                                               const float* __restrict__ prob,
                                               const float* __restrict__ zc,
                                               const float* __restrict__ c0,
                                               const float* __restrict__ zg) {
    int m = blockIdx.x;
    int b = m >> 7;
    int tid = threadIdx.x;
    float p = prob[m];
    float A1 = p / zg[m];
    float A2 = (1.0f - p) / zc[m];
    float cc = c0[m];
    const float* ev = e_vals + (size_t)m * SS;
    float4* row = reinterpret_cast<float4*>(gen + (size_t)m * VV);
    const int4* pm = reinterpret_cast<const int4*>(pos_map + b * VV);
    if constexpr (RD16 == 1) {
        const ushort8v* erow = reinterpret_cast<const ushort8v*>(ebuf + (size_t)m * VV);
        for (int i = tid; i < VV / 8; i += 256) {
            ushort8v ee = erow[i];
            int4 rp0 = pm[2 * i], rp1 = pm[2 * i + 1];
            float4 o0, o1;
            o0.x = __logf(A1 * bf2f(ee[0]) + A2 * ((rp0.x < SS) ? ev[rp0.x] : cc));
            o0.y = __logf(A1 * bf2f(ee[1]) + A2 * ((rp0.y < SS) ? ev[rp0.y] : cc));
            o0.z = __logf(A1 * bf2f(ee[2]) + A2 * ((rp0.z < SS) ? ev[rp0.z] : cc));
            o0.w = __logf(A1 * bf2f(ee[3]) + A2 * ((rp0.w < SS) ? ev[rp0.w] : cc));
            o1.x = __logf(A1 * bf2f(ee[4]) + A2 * ((rp1.x < SS) ? ev[rp1.x] : cc));
            o1.y = __logf(A1 * bf2f(ee[5]) + A2 * ((rp1.y < SS) ? ev[rp1.y] : cc));
            o1.z = __logf(A1 * bf2f(ee[6]) + A2 * ((rp1.z < SS) ? ev[rp1.z] : cc));
            o1.w = __logf(A1 * bf2f(ee[7]) + A2 * ((rp1.w < SS) ? ev[rp1.w] : cc));
            row[2 * i] = o0;
            row[2 * i + 1] = o1;
        }
    } else {
        for (int i = tid; i < VV / 4; i += 256) {
            float4 g = row[i];
            int4 rp = pm[i];
            float4 o;
            o.x = __logf(A1 * __expf(g.x) + A2 * ((rp.x < SS) ? ev[rp.x] : cc));
            o.y = __logf(A1 * __expf(g.y) + A2 * ((rp.y < SS) ? ev[rp.y] : cc));
            o.z = __logf(A1 * __expf(g.z) + A2 * ((rp.z < SS) ? ev[rp.z] : cc));
            o.w = __logf(A1 * __expf(g.w) + A2 * ((rp.w < SS) ? ev[rp.w] : cc));
            row[i] = o;
        }
    }
}

extern "C" void kernel_launch(void* const* d_in, const int* in_sizes, int n_in,
                              void* d_out, int out_size, void* d_ws, size_t ws_size,
                              hipStream_t stream) {
    const int* src = (const int*)d_in[0];
    const float* dec = (const float*)d_in[1];
    const float* dattn = (const float*)d_in[2];
    const float* mem = (const float*)d_in[3];
    const float* wgen = (const float*)d_in[4];
    const float* bgen = (const float*)d_in[5];
    const float* wprob = (const float*)d_in[6];
    const float* bprob = (const float*)d_in[7];
    float* out = (float*)d_out;
    char* ws = (char*)d_ws;

    // ws layout
    int* pos_map = (int*)(ws + 0);                       // 1,024,000 B (pad 1 MB)
    float* e_vals = (float*)(ws + 1048576);              // 2 MB
    float* mw   = (float*)(ws + 3145728);                // 16 KB
    float* dw   = (float*)(ws + 3145728 + 16384);
    float* prob = (float*)(ws + 3145728 + 20480);
    float* zc   = (float*)(ws + 3145728 + 24576);
    float* c0   = (float*)(ws + 3145728 + 28672);
    float* zg   = (float*)(ws + 3145728 + 32768);
    unsigned short* Wbf = (unsigned short*)(ws + 3211264);              // 65,536,000 B
    unsigned short* Abf = (unsigned short*)(ws + 3211264 + 65536000);   // 2 MB
    unsigned short* Ebf = (unsigned short*)(ws + 3211264 + 65536000 + 2097152);  // 65,536,000 B
    const size_t NEEDED  = 3211264ull + 65536000ull + 2097152ull;
    const size_t NEEDED2 = NEEDED + 65536000ull;

    bool do_cast = ws_size >= NEEDED;

    // pos_map "infinity" = 0x7F7F7F7F (> any s in [0,512)); zg = 0.0f
    hipMemsetAsync(pos_map, 0x7F, (size_t)BB * VV * sizeof(int), stream);
    hipMemsetAsync(zg, 0, (size_t)MM * sizeof(float), stream);

    k_setup1<<<do_cast ? 680 : 648, 512, 0, stream>>>(
        src, pos_map, mem, dec, wprob, mw, dw, do_cast ? Abf : nullptr);
    k_rowcast<<<do_cast ? (MM + 2048) : MM, 256, 0, stream>>>(
        dattn, src, pos_map, mw, dw, bprob, e_vals, prob, zc, c0,
        wgen, do_cast ? Wbf : nullptr);

    if (do_cast) {
        if (ws_size >= NEEDED2) {
            k_gemm_bf<1><<<(MM / 128) * (VV / 256), 512, 0, stream>>>(Abf, Wbf, bgen, out, Ebf, zg);
            k_final<1><<<MM, 256, 0, stream>>>(out, Ebf, pos_map, e_vals, prob, zc, c0, zg);
        } else {
            k_gemm_bf<0><<<(MM / 128) * (VV / 256), 512, 0, stream>>>(Abf, Wbf, bgen, out, Ebf, zg);
            k_final<0><<<MM, 256, 0, stream>>>(out, Ebf, pos_map, e_vals, prob, zc, c0, zg);
        }
    } else {
        k_gemm_f32<<<(MM / FBb) * (VV / FBb), 256, 0, stream>>>(dec, wgen, bgen, out, zg);
        k_final<0><<<MM, 256, 0, stream>>>(out, Ebf, pos_map, e_vals, prob, zc, c0, zg);
    }
}

// Round 14
// 209.571 us; speedup vs baseline: 1.0743x; 1.0267x over previous
//
#include <hip/hip_runtime.h>
#include <hip/hip_bf16.h>
#include <cstddef>
#include <cstdint>

// Problem constants
#define BB 8
#define HH 16
#define TT 128
#define SS 512
#define DD 1024
#define VV 32000
#define MM (BB * TT)   // 1024 output rows

typedef float f32x4 __attribute__((ext_vector_type(4)));
typedef short short8v __attribute__((ext_vector_type(8)));
typedef unsigned short ushort8v __attribute__((ext_vector_type(8)));

__device__ __forceinline__ unsigned short f2bf(float x) {
    __hip_bfloat16 h = __float2bfloat16(x);
    return __builtin_bit_cast(unsigned short, h);
}
__device__ __forceinline__ float bf2f(unsigned short u) {
    unsigned int x = ((unsigned int)u) << 16;
    return __builtin_bit_cast(float, x);
}

__device__ __forceinline__ float wave_sum(float v) {
#pragma unroll
    for (int o = 1; o < 64; o <<= 1) v += __shfl_xor(v, o);
    return v;
}
__device__ __forceinline__ float wave_max(float v) {
#pragma unroll
    for (int o = 1; o < 64; o <<= 1) v = fmaxf(v, __shfl_xor(v, o));
    return v;
}
__device__ __forceinline__ float block_sum(float v, float* red, int tid) {
    v = wave_sum(v);
    __syncthreads();
    if ((tid & 63) == 0) red[tid >> 6] = v;
    __syncthreads();
    return red[0] + red[1] + red[2] + red[3];
}
__device__ __forceinline__ float block_max(float v, float* red, int tid) {
    v = wave_max(v);
    __syncthreads();
    if ((tid & 63) == 0) red[tid >> 6] = v;
    __syncthreads();
    return fmaxf(fmaxf(red[0], red[1]), fmaxf(red[2], red[3]));
}

// ---------------- merged setup: pm_build | vecdots | cast-W | cast-A ----------------
// 512-thread blocks:
//   [0,8)        pm_build (pos_map pre-set to 0x7F7F7F7F by memset)
//   [8,648)      vecdots, 8 rows/block (5120 rows)
//   [648,1672)   cast W_gen f32->bf16, grid-stride (1024 blocks)  [if do_cast]
//   [1672,1704)  cast dec  f32->bf16, grid-stride (32 blocks)     [if do_cast]
__global__ __launch_bounds__(512) void k_setup(const int* __restrict__ src,
                                               int* __restrict__ pos_map,
                                               const float* __restrict__ memory,
                                               const float* __restrict__ dec,
                                               const float* __restrict__ wprob,
                                               float* __restrict__ mw,
                                               float* __restrict__ dw,
                                               const float* __restrict__ wgen,
                                               unsigned short* __restrict__ Wbf,
                                               unsigned short* __restrict__ Abf) {
    int blk = blockIdx.x, tid = threadIdx.x;
    if (blk < 8) {
        int tok = src[blk * SS + tid];
        atomicMin(&pos_map[blk * VV + tok], tid);
    } else if (blk < 648) {
        int row = (blk - 8) * 8 + (tid >> 6);
        int lane = tid & 63;
        const float4* srcv;
        const float4* wv;
        if (row < BB * SS) {
            srcv = reinterpret_cast<const float4*>(memory + (size_t)row * DD);
            wv = reinterpret_cast<const float4*>(wprob);
        } else {
            srcv = reinterpret_cast<const float4*>(dec + (size_t)(row - BB * SS) * DD);
            wv = reinterpret_cast<const float4*>(wprob + DD);
        }
        float sum = 0.f;
#pragma unroll
        for (int k = 0; k < 4; ++k) {
            int idx = lane + 64 * k;
            float4 a = srcv[idx];
            float4 w = wv[idx];
            sum += a.x * w.x + a.y * w.y + a.z * w.z + a.w * w.w;
        }
        sum = wave_sum(sum);
        if (lane == 0) {
            if (row < BB * SS) mw[row] = sum;
            else dw[row - BB * SS] = sum;
        }
    } else if (blk < 1672) {
        if (Wbf == nullptr) return;
        const int n8 = VV * DD / 8;
        for (int i = (blk - 648) * 512 + tid; i < n8; i += 1024 * 512) {
            const float4* p = reinterpret_cast<const float4*>(wgen + (size_t)i * 8);
            float4 a = p[0], b = p[1];
            ushort8v u;
            u[0] = f2bf(a.x); u[1] = f2bf(a.y); u[2] = f2bf(a.z); u[3] = f2bf(a.w);
            u[4] = f2bf(b.x); u[5] = f2bf(b.y); u[6] = f2bf(b.z); u[7] = f2bf(b.w);
            *reinterpret_cast<ushort8v*>(Wbf + (size_t)i * 8) = u;
        }
    } else {
        if (Abf == nullptr) return;
        const int n8 = MM * DD / 8;
        for (int i = (blk - 1672) * 512 + tid; i < n8; i += 32 * 512) {
            const float4* p = reinterpret_cast<const float4*>(dec + (size_t)i * 8);
            float4 a = p[0], b = p[1];
            ushort8v u;
            u[0] = f2bf(a.x); u[1] = f2bf(a.y); u[2] = f2bf(a.z); u[3] = f2bf(a.w);
            u[4] = f2bf(b.x); u[5] = f2bf(b.y); u[6] = f2bf(b.z); u[7] = f2bf(b.w);
            *reinterpret_cast<ushort8v*>(Abf + (size_t)i * 8) = u;
        }
    }
}

// =====================================================================
// 128x256 bf16 MFMA GEMM, 8 waves (64x64), BK=32, TRIPLE buffer, 2-deep
// prefetch, counted vmcnt(3). Conflict-free XOR swizzle (verified: 0
// conflicts). Settled: 5 structural variants all land 98-100 us — LDS
// pipe floor (~1900 cyc/iter/CU) + latency at the 64-VGPR/2-block wall.
// =====================================================================
#define NKT 32          // K tiles = 1024/32
#define BUFE 12288      // elems per buffer: A 128*32=4096 + B 256*32=8192

#define AS1 __attribute__((address_space(1)))
#define AS3 __attribute__((address_space(3)))

template <int EPI>
__global__ __launch_bounds__(512, 4) void k_gemm_bf(const unsigned short* __restrict__ Abf,
                                                    const unsigned short* __restrict__ Wbf,
                                                    const float* __restrict__ bgen,
                                                    float* __restrict__ out,
                                                    unsigned short* __restrict__ ebuf,
                                                    float* __restrict__ zg) {
    __shared__ unsigned short lds[3 * BUFE];   // 72 KiB

    int tid = threadIdx.x;
    int p = blockIdx.x;
    // bijective XCD swizzle: 1000 = 8 * 125
    int wgid = (p & 7) * 125 + (p >> 3);
    int mt = wgid & 7, nt = wgid >> 3;   // consecutive wg share nt -> W L2 reuse
    int m0 = mt * 128, v0 = nt * 256;

    int lane = tid & 63, w = tid >> 6;
    int wm = w & 1, wn = w >> 1;         // wave owns 64(M) x 64(N)

    // staging: pre-swizzled source chunk ((tid&3)^((tid>>3)&3)), linear LDS dest
    int srow = tid >> 2;                 // 0..127
    int schunk = (tid & 3) ^ ((tid >> 3) & 3);
    const unsigned short* gA = Abf + (size_t)(m0 + srow) * DD + schunk * 8;
    const unsigned short* gB = Wbf + (size_t)(v0 + srow) * DD + schunk * 8;

    // per tile: 1 A-load + 2 B-loads per thread (vmcnt granularity = 3)
#define STAGE(T, BI) do {                                                              \
    size_t ko_ = (size_t)(T) * 32;                                                     \
    __builtin_amdgcn_global_load_lds(                                                  \
        (const AS1 void*)(gA + ko_),                                                   \
        (AS3 void*)(lds + (BI) * BUFE + tid * 8), 16, 0, 0);                           \
    __builtin_amdgcn_global_load_lds(                                                  \
        (const AS1 void*)(gB + ko_),                                                   \
        (AS3 void*)(lds + (BI) * BUFE + 4096 + tid * 8), 16, 0, 0);                    \
    __builtin_amdgcn_global_load_lds(                                                  \
        (const AS1 void*)(gB + (size_t)128 * DD + ko_),                                \
        (AS3 void*)(lds + (BI) * BUFE + 8192 + tid * 8), 16, 0, 0);                    \
} while (0)

    // fragment reads: row base multiple of 16 -> xr depends only on lr
    int lr = lane & 15, kg = lane >> 4;
    int xr = (lr >> 1) & 3;
    const unsigned short* arow = lds + (wm * 64 + lr) * 32 + ((kg ^ xr) << 3);
    const unsigned short* brow = lds + 4096 + (wn * 64 + lr) * 32 + ((kg ^ xr) << 3);

    f32x4 acc[4][4] = {};

#define ITER(T, BI, DO_STAGE, VM)  do {                                                \
    __builtin_amdgcn_s_barrier();                                                      \
    short8v af[4], bfr[4];                                                             \
    _Pragma("unroll")                                                                  \
    for (int i = 0; i < 4; ++i) {                                                      \
        af[i] = *reinterpret_cast<const short8v*>(arow + (BI) * BUFE + i * 512);       \
        bfr[i] = *reinterpret_cast<const short8v*>(brow + (BI) * BUFE + i * 512);      \
    }                                                                                  \
    if (DO_STAGE) STAGE((T) + 2, ((BI) + 2) % 3);                                      \
    __builtin_amdgcn_s_setprio(1);                                                     \
    _Pragma("unroll")                                                                  \
    for (int i = 0; i < 4; ++i)                                                        \
        _Pragma("unroll")                                                              \
        for (int j = 0; j < 4; ++j)                                                    \
            acc[i][j] = __builtin_amdgcn_mfma_f32_16x16x32_bf16(af[i], bfr[j], acc[i][j], 0, 0, 0); \
    __builtin_amdgcn_s_setprio(0);                                                     \
    if ((VM) == 3) asm volatile("s_waitcnt vmcnt(3)" ::: "memory");                    \
    else if ((VM) == 0) asm volatile("s_waitcnt vmcnt(0)" ::: "memory");               \
} while (0)

    // prologue: stage tiles 0,1; wait tile 0 (3 newest = tile 1 still in flight)
    STAGE(0, 0);
    STAGE(1, 1);
    asm volatile("s_waitcnt vmcnt(3)" ::: "memory");

    for (int t = 0; t < NKT - 2; t += 3) {
        ITER(t + 0, 0, true, 3);
        ITER(t + 1, 1, true, 3);
        ITER(t + 2, 2, true, 3);
    }
    ITER(30, 0, false, 0);
    ITER(31, 1, false, -1);
#undef ITER
#undef STAGE

    // ---- epilogue: bias + exp + store + per-row exp-sum atomics
    int colb = lane & 15, rgrp = lane >> 4;
#pragma unroll
    for (int i = 0; i < 4; ++i) {
        float es0 = 0.f, es1 = 0.f, es2 = 0.f, es3 = 0.f;
        int gmb = m0 + wm * 64 + i * 16 + rgrp * 4;
#pragma unroll
        for (int j = 0; j < 4; ++j) {
            int gv = v0 + wn * 64 + j * 16 + colb;
            float bgj = bgen[gv];
            float v0f = acc[i][j][0] + bgj;
            float v1f = acc[i][j][1] + bgj;
            float v2f = acc[i][j][2] + bgj;
            float v3f = acc[i][j][3] + bgj;
            float e0 = __expf(v0f), e1 = __expf(v1f), e2 = __expf(v2f), e3 = __expf(v3f);
            if constexpr (EPI == 1) {
                ebuf[(size_t)(gmb + 0) * VV + gv] = f2bf(e0);
                ebuf[(size_t)(gmb + 1) * VV + gv] = f2bf(e1);
                ebuf[(size_t)(gmb + 2) * VV + gv] = f2bf(e2);
                ebuf[(size_t)(gmb + 3) * VV + gv] = f2bf(e3);
            } else {
                out[(size_t)(gmb + 0) * VV + gv] = v0f;
                out[(size_t)(gmb + 1) * VV + gv] = v1f;
                out[(size_t)(gmb + 2) * VV + gv] = v2f;
                out[(size_t)(gmb + 3) * VV + gv] = v3f;
            }
            es0 += e0; es1 += e1; es2 += e2; es3 += e3;
        }
        float es[4] = {es0, es1, es2, es3};
#pragma unroll
        for (int rr = 0; rr < 4; ++rr) {
            float e = es[rr];
            e += __shfl_xor(e, 1); e += __shfl_xor(e, 2);
            e += __shfl_xor(e, 4); e += __shfl_xor(e, 8);
            if (colb == 0) atomicAdd(&zg[gmb + rr], e);
        }
    }
}

// ---------------- fallback GEMM (f32 inputs, in-register cast, 128^2) ----------------
#define FBb 128
#define FLDK 40

__global__ __launch_bounds__(256) void k_gemm_f32(const float* __restrict__ A,
                                                  const float* __restrict__ Wg,
                                                  const float* __restrict__ bgen,
                                                  float* __restrict__ out,
                                                  float* __restrict__ zg) {
    __shared__ unsigned short As[FBb * FLDK];
    __shared__ unsigned short Bs[FBb * FLDK];
    int tid = threadIdx.x;
    int bid = blockIdx.x;
    int mt = bid & 7;
    int nt = bid >> 3;
    int m0 = mt * FBb, v0 = nt * FBb;
    int lane = tid & 63, wid = tid >> 6;
    int wr = (wid >> 1) * 64, wc = (wid & 1) * 64;
    int lr = lane & 15, lk = (lane >> 4) << 3;
    int r = tid >> 1, c0 = (tid & 1) << 4;

    f32x4 acc[4][4] = {};

    for (int k0 = 0; k0 < DD; k0 += 32) {
        {
            const float4* pa = reinterpret_cast<const float4*>(A + (size_t)(m0 + r) * DD + k0 + c0);
            float4 x0 = pa[0], x1 = pa[1], x2 = pa[2], x3 = pa[3];
            ushort8v u0, u1;
            u0[0] = f2bf(x0.x); u0[1] = f2bf(x0.y); u0[2] = f2bf(x0.z); u0[3] = f2bf(x0.w);
            u0[4] = f2bf(x1.x); u0[5] = f2bf(x1.y); u0[6] = f2bf(x1.z); u0[7] = f2bf(x1.w);
            u1[0] = f2bf(x2.x); u1[1] = f2bf(x2.y); u1[2] = f2bf(x2.z); u1[3] = f2bf(x2.w);
            u1[4] = f2bf(x3.x); u1[5] = f2bf(x3.y); u1[6] = f2bf(x3.z); u1[7] = f2bf(x3.w);
            *reinterpret_cast<ushort8v*>(&As[r * FLDK + c0]) = u0;
            *reinterpret_cast<ushort8v*>(&As[r * FLDK + c0 + 8]) = u1;

            const float4* pb = reinterpret_cast<const float4*>(Wg + (size_t)(v0 + r) * DD + k0 + c0);
            float4 y0 = pb[0], y1 = pb[1], y2 = pb[2], y3 = pb[3];
            ushort8v w0, w1;
            w0[0] = f2bf(y0.x); w0[1] = f2bf(y0.y); w0[2] = f2bf(y0.z); w0[3] = f2bf(y0.w);
            w0[4] = f2bf(y1.x); w0[5] = f2bf(y1.y); w0[6] = f2bf(y1.z); w0[7] = f2bf(y1.w);
            w1[0] = f2bf(y2.x); w1[1] = f2bf(y2.y); w1[2] = f2bf(y2.z); w1[3] = f2bf(y2.w);
            w1[4] = f2bf(y3.x); w1[5] = f2bf(y3.y); w1[6] = f2bf(y3.z); w1[7] = f2bf(y3.w);
            *reinterpret_cast<ushort8v*>(&Bs[r * FLDK + c0]) = w0;
            *reinterpret_cast<ushort8v*>(&Bs[r * FLDK + c0 + 8]) = w1;
        }
        __syncthreads();

        short8v af[4], bfr[4];
#pragma unroll
        for (int i = 0; i < 4; ++i)
            af[i] = *reinterpret_cast<const short8v*>(&As[(wr + i * 16 + lr) * FLDK + lk]);
#pragma unroll
        for (int j = 0; j < 4; ++j)
            bfr[j] = *reinterpret_cast<const short8v*>(&Bs[(wc + j * 16 + lr) * FLDK + lk]);
#pragma unroll
        for (int i = 0; i < 4; ++i)
#pragma unroll
            for (int j = 0; j < 4; ++j)
                acc[i][j] = __builtin_amdgcn_mfma_f32_16x16x32_bf16(af[i], bfr[j], acc[i][j], 0, 0, 0);
        __syncthreads();
    }

    int colb = lane & 15;
    int rgrp = lane >> 4;
#pragma unroll
    for (int i = 0; i < 4; ++i) {
        float es0 = 0.f, es1 = 0.f, es2 = 0.f, es3 = 0.f;
        int gmb = m0 + wr + i * 16 + rgrp * 4;
#pragma unroll
        for (int j = 0; j < 4; ++j) {
            int gv = v0 + wc + j * 16 + colb;
            float bgj = bgen[gv];
            float v0f = acc[i][j][0] + bgj;
            float v1f = acc[i][j][1] + bgj;
            float v2f = acc[i][j][2] + bgj;
            float v3f = acc[i][j][3] + bgj;
            out[(size_t)(gmb + 0) * VV + gv] = v0f;
            out[(size_t)(gmb + 1) * VV + gv] = v1f;
            out[(size_t)(gmb + 2) * VV + gv] = v2f;
            out[(size_t)(gmb + 3) * VV + gv] = v3f;
            es0 += __expf(v0f); es1 += __expf(v1f);
            es2 += __expf(v2f); es3 += __expf(v3f);
        }
        float es[4] = {es0, es1, es2, es3};
#pragma unroll
        for (int rr = 0; rr < 4; ++rr) {
            float e = es[rr];
            e += __shfl_xor(e, 1); e += __shfl_xor(e, 2);
            e += __shfl_xor(e, 4); e += __shfl_xor(e, 8);
            if (colb == 0) atomicAdd(&zg[gmb + rr], e);
        }
    }
}

// ---------------- merged row + final combine (one block per output row) ----------------
// Phase 1 = former k_row: head-mean, scatter, prob gate, copy-Z — all in LDS
// (e_vals/prob/zc/c0 never touch HBM). Phase 2 = combine into d_out.
// RD16=1: read bf16 exp(logit) from ebuf. RD16=0: read f32 logits in-place.
template <int RD16>
__global__ __launch_bounds__(256) void k_final(float* __restrict__ gen,
                                               const unsigned short* __restrict__ ebuf,
                                               const float* __restrict__ dattn,
                                               const int* __restrict__ src,
                                               const int* __restrict__ pos_map,
                                               const float* __restrict__ mw,
                                               const float* __restrict__ dw,
                                               const float* __restrict__ bprob,
                                               const float* __restrict__ zg) {
    int m = blockIdx.x;
    int b = m >> 7;
    int t = m & 127;
    int tid = threadIdx.x;
    __shared__ float a_row[SS];
    __shared__ float vals[SS];
    __shared__ int reps[SS];
    __shared__ float evs[SS];
    __shared__ float red[4];
    __shared__ float sA1, sA2, scc;

    // ---- phase 1: head mean (float2-vectorized) + rep cache
    {
        const float2* base = reinterpret_cast<const float2*>(
            dattn + ((size_t)b * HH * TT + t) * SS) + tid;
        float sx = 0.f, sy = 0.f;
#pragma unroll
        for (int h = 0; h < HH; ++h) {
            float2 v = base[(size_t)h * (TT * SS / 2)];
            sx += v.x; sy += v.y;
        }
        a_row[2 * tid] = sx * 0.0625f;
        a_row[2 * tid + 1] = sy * 0.0625f;
        vals[2 * tid] = 0.f;
        vals[2 * tid + 1] = 0.f;
    }
    {
        int s0 = 2 * tid, s1 = 2 * tid + 1;
        reps[s0] = pos_map[b * VV + src[b * SS + s0]];
        reps[s1] = pos_map[b * VV + src[b * SS + s1]];
    }
    __syncthreads();
    for (int s = tid; s < SS; s += 256) {
        atomicAdd(&vals[reps[s]], a_row[s]);
    }
    __syncthreads();
    float psum = 0.f;
    for (int s = tid; s < SS; s += 256) psum += a_row[s] * mw[b * SS + s];
    psum = block_sum(psum, red, tid);
    float z = psum + dw[m] + bprob[0];
    float p = 1.0f / (1.0f + __expf(-z));
    float mxv = -3.4e38f;
    for (int s = tid; s < SS; s += 256) {
        if (reps[s] == s) mxv = fmaxf(mxv, vals[s]);
    }
    mxv = block_max(mxv, red, tid);
    float m_c = fmaxf(0.0f, mxv);
    float sexp = 0.f, cnt = 0.f;
    for (int s = tid; s < SS; s += 256) {
        float e = 0.0f;
        if (reps[s] == s) {
            e = __expf(vals[s] - m_c);
            sexp += e;
            cnt += 1.0f;
        }
        evs[s] = e;
    }
    sexp = block_sum(sexp, red, tid);
    cnt = block_sum(cnt, red, tid);
    if (tid == 0) {
        float cc = __expf(-m_c);
        float zcv = ((float)VV - cnt) * cc + sexp;
        sA1 = p / zg[m];
        sA2 = (1.0f - p) / zcv;
        scc = cc;
    }
    __syncthreads();

    // ---- phase 2: combine into d_out
    float A1 = sA1, A2 = sA2, cc = scc;
    float4* row = reinterpret_cast<float4*>(gen + (size_t)m * VV);
    const int4* pm = reinterpret_cast<const int4*>(pos_map + b * VV);
    if constexpr (RD16 == 1) {
        const ushort8v* erow = reinterpret_cast<const ushort8v*>(ebuf + (size_t)m * VV);
        for (int i = tid; i < VV / 8; i += 256) {
            ushort8v ee = erow[i];
            int4 rp0 = pm[2 * i], rp1 = pm[2 * i + 1];
            float4 o0, o1;
            o0.x = __logf(A1 * bf2f(ee[0]) + A2 * ((rp0.x < SS) ? evs[rp0.x] : cc));
            o0.y = __logf(A1 * bf2f(ee[1]) + A2 * ((rp0.y < SS) ? evs[rp0.y] : cc));
            o0.z = __logf(A1 * bf2f(ee[2]) + A2 * ((rp0.z < SS) ? evs[rp0.z] : cc));
            o0.w = __logf(A1 * bf2f(ee[3]) + A2 * ((rp0.w < SS) ? evs[rp0.w] : cc));
            o1.x = __logf(A1 * bf2f(ee[4]) + A2 * ((rp1.x < SS) ? evs[rp1.x] : cc));
            o1.y = __logf(A1 * bf2f(ee[5]) + A2 * ((rp1.y < SS) ? evs[rp1.y] : cc));
            o1.z = __logf(A1 * bf2f(ee[6]) + A2 * ((rp1.z < SS) ? evs[rp1.z] : cc));
            o1.w = __logf(A1 * bf2f(ee[7]) + A2 * ((rp1.w < SS) ? evs[rp1.w] : cc));
            row[2 * i] = o0;
            row[2 * i + 1] = o1;
        }
    } else {
        for (int i = tid; i < VV / 4; i += 256) {
            float4 g = row[i];
            int4 rp = pm[i];
            float4 o;
            o.x = __logf(A1 * __expf(g.x) + A2 * ((rp.x < SS) ? evs[rp.x] : cc));
            o.y = __logf(A1 * __expf(g.y) + A2 * ((rp.y < SS) ? evs[rp.y] : cc));
            o.z = __logf(A1 * __expf(g.z) + A2 * ((rp.z < SS) ? evs[rp.z] : cc));
            o.w = __logf(A1 * __expf(g.w) + A2 * ((rp.w < SS) ? evs[rp.w] : cc));
            row[i] = o;
        }
    }
}

extern "C" void kernel_launch(void* const* d_in, const int* in_sizes, int n_in,
                              void* d_out, int out_size, void* d_ws, size_t ws_size,
                              hipStream_t stream) {
    const int* src = (const int*)d_in[0];
    const float* dec = (const float*)d_in[1];
    const float* dattn = (const float*)d_in[2];
    const float* mem = (const float*)d_in[3];
    const float* wgen = (const float*)d_in[4];
    const float* bgen = (const float*)d_in[5];
    const float* wprob = (const float*)d_in[6];
    const float* bprob = (const float*)d_in[7];
    float* out = (float*)d_out;
    char* ws = (char*)d_ws;

    // ws layout
    int* pos_map = (int*)(ws + 0);                       // 1,024,000 B (pad 1 MB)
    float* mw   = (float*)(ws + 1048576);                // 16 KB
    float* dw   = (float*)(ws + 1048576 + 16384);
    float* zg   = (float*)(ws + 1048576 + 24576);        // 4 KB
    unsigned short* Wbf = (unsigned short*)(ws + 1114112);              // 65,536,000 B
    unsigned short* Abf = (unsigned short*)(ws + 1114112 + 65536000);   // 2 MB
    unsigned short* Ebf = (unsigned short*)(ws + 1114112 + 65536000 + 2097152);  // 65,536,000 B
    const size_t NEEDED  = 1114112ull + 65536000ull + 2097152ull;
    const size_t NEEDED2 = NEEDED + 65536000ull;

    bool do_cast = ws_size >= NEEDED;

    // pos_map "infinity" = 0x7F7F7F7F (> any s in [0,512)); zg = 0.0f
    hipMemsetAsync(pos_map, 0x7F, (size_t)BB * VV * sizeof(int), stream);
    hipMemsetAsync(zg, 0, (size_t)MM * sizeof(float), stream);

    k_setup<<<do_cast ? 1704 : 648, 512, 0, stream>>>(
        src, pos_map, mem, dec, wprob, mw, dw, wgen,
        do_cast ? Wbf : nullptr, do_cast ? Abf : nullptr);

    if (do_cast) {
        if (ws_size >= NEEDED2) {
            k_gemm_bf<1><<<(MM / 128) * (VV / 256), 512, 0, stream>>>(Abf, Wbf, bgen, out, Ebf, zg);
            k_final<1><<<MM, 256, 0, stream>>>(out, Ebf, dattn, src, pos_map, mw, dw, bprob, zg);
        } else {
            k_gemm_bf<0><<<(MM / 128) * (VV / 256), 512, 0, stream>>>(Abf, Wbf, bgen, out, Ebf, zg);
            k_final<0><<<MM, 256, 0, stream>>>(out, Ebf, dattn, src, pos_map, mw, dw, bprob, zg);
        }
    } else {
        k_gemm_f32<<<(MM / FBb) * (VV / FBb), 256, 0, stream>>>(dec, wgen, bgen, out, zg);
        k_final<0><<<MM, 256, 0, stream>>>(out, Ebf, dattn, src, pos_map, mw, dw, bprob, zg);
    }
}

// Round 15
// 208.522 us; speedup vs baseline: 1.0797x; 1.0050x over previous
//
#include <hip/hip_runtime.h>
#include <hip/hip_bf16.h>
#include <cstddef>
#include <cstdint>

// Problem constants
#define BB 8
#define HH 16
#define TT 128
#define SS 512
#define DD 1024
#define VV 32000
#define MM (BB * TT)   // 1024 output rows

typedef float f32x4 __attribute__((ext_vector_type(4)));
typedef short short8v __attribute__((ext_vector_type(8)));
typedef unsigned short ushort8v __attribute__((ext_vector_type(8)));

__device__ __forceinline__ unsigned short f2bf(float x) {
    __hip_bfloat16 h = __float2bfloat16(x);
    return __builtin_bit_cast(unsigned short, h);
}
__device__ __forceinline__ float bf2f(unsigned short u) {
    unsigned int x = ((unsigned int)u) << 16;
    return __builtin_bit_cast(float, x);
}

__device__ __forceinline__ float wave_sum(float v) {
#pragma unroll
    for (int o = 1; o < 64; o <<= 1) v += __shfl_xor(v, o);
    return v;
}
__device__ __forceinline__ float wave_max(float v) {
#pragma unroll
    for (int o = 1; o < 64; o <<= 1) v = fmaxf(v, __shfl_xor(v, o));
    return v;
}
// 512-thread (8-wave) block reductions
__device__ __forceinline__ float block_sum8(float v, float* red, int tid) {
    v = wave_sum(v);
    __syncthreads();
    if ((tid & 63) == 0) red[tid >> 6] = v;
    __syncthreads();
    return red[0] + red[1] + red[2] + red[3] + red[4] + red[5] + red[6] + red[7];
}
__device__ __forceinline__ float block_max8(float v, float* red, int tid) {
    v = wave_max(v);
    __syncthreads();
    if ((tid & 63) == 0) red[tid >> 6] = v;
    __syncthreads();
    float a = fmaxf(fmaxf(red[0], red[1]), fmaxf(red[2], red[3]));
    float b = fmaxf(fmaxf(red[4], red[5]), fmaxf(red[6], red[7]));
    return fmaxf(a, b);
}

// ---------------- merged setup: pm_build | vecdots | cast-W | cast-A ----------------
// 512-thread blocks:
//   [0,8)        pm_build (pos_map pre-set to 0x7F7F7F7F by memset)
//   [8,648)      vecdots, 8 rows/block (5120 rows)
//   [648,1672)   cast W_gen f32->bf16, grid-stride (1024 blocks)  [if do_cast]
//   [1672,1704)  cast dec  f32->bf16, grid-stride (32 blocks)     [if do_cast]
__global__ __launch_bounds__(512) void k_setup(const int* __restrict__ src,
                                               int* __restrict__ pos_map,
                                               const float* __restrict__ memory,
                                               const float* __restrict__ dec,
                                               const float* __restrict__ wprob,
                                               float* __restrict__ mw,
                                               float* __restrict__ dw,
                                               const float* __restrict__ wgen,
                                               unsigned short* __restrict__ Wbf,
                                               unsigned short* __restrict__ Abf) {
    int blk = blockIdx.x, tid = threadIdx.x;
    if (blk < 8) {
        int tok = src[blk * SS + tid];
        atomicMin(&pos_map[blk * VV + tok], tid);
    } else if (blk < 648) {
        int row = (blk - 8) * 8 + (tid >> 6);
        int lane = tid & 63;
        const float4* srcv;
        const float4* wv;
        if (row < BB * SS) {
            srcv = reinterpret_cast<const float4*>(memory + (size_t)row * DD);
            wv = reinterpret_cast<const float4*>(wprob);
        } else {
            srcv = reinterpret_cast<const float4*>(dec + (size_t)(row - BB * SS) * DD);
            wv = reinterpret_cast<const float4*>(wprob + DD);
        }
        float sum = 0.f;
#pragma unroll
        for (int k = 0; k < 4; ++k) {
            int idx = lane + 64 * k;
            float4 a = srcv[idx];
            float4 w = wv[idx];
            sum += a.x * w.x + a.y * w.y + a.z * w.z + a.w * w.w;
        }
        sum = wave_sum(sum);
        if (lane == 0) {
            if (row < BB * SS) mw[row] = sum;
            else dw[row - BB * SS] = sum;
        }
    } else if (blk < 1672) {
        if (Wbf == nullptr) return;
        const int n8 = VV * DD / 8;
        for (int i = (blk - 648) * 512 + tid; i < n8; i += 1024 * 512) {
            const float4* p = reinterpret_cast<const float4*>(wgen + (size_t)i * 8);
            float4 a = p[0], b = p[1];
            ushort8v u;
            u[0] = f2bf(a.x); u[1] = f2bf(a.y); u[2] = f2bf(a.z); u[3] = f2bf(a.w);
            u[4] = f2bf(b.x); u[5] = f2bf(b.y); u[6] = f2bf(b.z); u[7] = f2bf(b.w);
            *reinterpret_cast<ushort8v*>(Wbf + (size_t)i * 8) = u;
        }
    } else {
        if (Abf == nullptr) return;
        const int n8 = MM * DD / 8;
        for (int i = (blk - 1672) * 512 + tid; i < n8; i += 32 * 512) {
            const float4* p = reinterpret_cast<const float4*>(dec + (size_t)i * 8);
            float4 a = p[0], b = p[1];
            ushort8v u;
            u[0] = f2bf(a.x); u[1] = f2bf(a.y); u[2] = f2bf(a.z); u[3] = f2bf(a.w);
            u[4] = f2bf(b.x); u[5] = f2bf(b.y); u[6] = f2bf(b.z); u[7] = f2bf(b.w);
            *reinterpret_cast<ushort8v*>(Abf + (size_t)i * 8) = u;
        }
    }
}

// =====================================================================
// 128x128 bf16 MFMA GEMM, 4 waves (64x64 each), BK=32, TRIPLE buffer,
// 2-deep prefetch, counted vmcnt(4). 49 KiB LDS -> 3 blocks/CU (more
// independent barrier domains: R14 audit showed 99us vs ~28us LDS floor
// = barrier/latency stall; m114 overlap needs block diversity).
// Same verified conflict-free XOR swizzle (row stride 64B unchanged).
// Grid 2000 = 8 XCD x 250 bijective swizzle.
// =====================================================================
#define NKT 32          // K tiles = 1024/32
#define BUFE 8192       // elems per buffer: A 128*32=4096 + B 128*32=4096

#define AS1 __attribute__((address_space(1)))
#define AS3 __attribute__((address_space(3)))

template <int EPI>
__global__ __launch_bounds__(256, 4) void k_gemm_bf(const unsigned short* __restrict__ Abf,
                                                    const unsigned short* __restrict__ Wbf,
                                                    const float* __restrict__ bgen,
                                                    float* __restrict__ out,
                                                    unsigned short* __restrict__ ebuf,
                                                    float* __restrict__ zg) {
    __shared__ unsigned short lds[3 * BUFE];   // 48 KiB

    int tid = threadIdx.x;
    int p = blockIdx.x;
    // bijective XCD swizzle: 2000 = 8 * 250
    int wgid = (p & 7) * 250 + (p >> 3);
    int mt = wgid & 7, nt = wgid >> 3;   // consecutive wg share nt -> W L2 reuse
    int m0 = mt * 128, v0 = nt * 128;

    int lane = tid & 63, w = tid >> 6;   // 4 waves
    int wm = w & 1, wn = w >> 1;         // 2(M) x 2(N); wave owns 64x64

    // staging: row = tid>>2 (0..63 per issue), chunk pre-swizzled with
    // ((row>>1)&3) = ((tid>>3)&3) — same verified formula (row stride 64B).
    int srow = tid >> 2;
    int schunk = (tid & 3) ^ ((tid >> 3) & 3);
    const unsigned short* gA = Abf + (size_t)(m0 + srow) * DD + schunk * 8;
    const unsigned short* gB = Wbf + (size_t)(v0 + srow) * DD + schunk * 8;

    // per tile: 2 A-issues + 2 B-issues (64 rows each); vmcnt granularity = 4
#define STAGE(T, BI) do {                                                              \
    size_t ko_ = (size_t)(T) * 32;                                                     \
    __builtin_amdgcn_global_load_lds(                                                  \
        (const AS1 void*)(gA + ko_),                                                   \
        (AS3 void*)(lds + (BI) * BUFE + tid * 8), 16, 0, 0);                           \
    __builtin_amdgcn_global_load_lds(                                                  \
        (const AS1 void*)(gA + (size_t)64 * DD + ko_),                                 \
        (AS3 void*)(lds + (BI) * BUFE + 2048 + tid * 8), 16, 0, 0);                    \
    __builtin_amdgcn_global_load_lds(                                                  \
        (const AS1 void*)(gB + ko_),                                                   \
        (AS3 void*)(lds + (BI) * BUFE + 4096 + tid * 8), 16, 0, 0);                    \
    __builtin_amdgcn_global_load_lds(                                                  \
        (const AS1 void*)(gB + (size_t)64 * DD + ko_),                                 \
        (AS3 void*)(lds + (BI) * BUFE + 6144 + tid * 8), 16, 0, 0);                    \
} while (0)

    // fragment reads: row base multiple of 16 -> xr depends only on lr
    int lr = lane & 15, kg = lane >> 4;
    int xr = (lr >> 1) & 3;
    const unsigned short* arow = lds + (wm * 64 + lr) * 32 + ((kg ^ xr) << 3);
    const unsigned short* brow = lds + 4096 + (wn * 64 + lr) * 32 + ((kg ^ xr) << 3);

    f32x4 acc[4][4] = {};

#define ITER(T, BI, DO_STAGE, VM)  do {                                                \
    __builtin_amdgcn_s_barrier();                                                      \
    short8v af[4], bfr[4];                                                             \
    _Pragma("unroll")                                                                  \
    for (int i = 0; i < 4; ++i) {                                                      \
        af[i] = *reinterpret_cast<const short8v*>(arow + (BI) * BUFE + i * 512);       \
        bfr[i] = *reinterpret_cast<const short8v*>(brow + (BI) * BUFE + i * 512);      \
    }                                                                                  \
    if (DO_STAGE) STAGE((T) + 2, ((BI) + 2) % 3);                                      \
    __builtin_amdgcn_s_setprio(1);                                                     \
    _Pragma("unroll")                                                                  \
    for (int i = 0; i < 4; ++i)                                                        \
        _Pragma("unroll")                                                              \
        for (int j = 0; j < 4; ++j)                                                    \
            acc[i][j] = __builtin_amdgcn_mfma_f32_16x16x32_bf16(af[i], bfr[j], acc[i][j], 0, 0, 0); \
    __builtin_amdgcn_s_setprio(0);                                                     \
    if ((VM) == 4) asm volatile("s_waitcnt vmcnt(4)" ::: "memory");                    \
    else if ((VM) == 0) asm volatile("s_waitcnt vmcnt(0)" ::: "memory");               \
} while (0)

    // prologue: stage tiles 0,1 (8 outstanding); wait tile 0 (newest 4 = tile 1)
    STAGE(0, 0);
    STAGE(1, 1);
    asm volatile("s_waitcnt vmcnt(4)" ::: "memory");

    for (int t = 0; t < NKT - 2; t += 3) {
        ITER(t + 0, 0, true, 4);
        ITER(t + 1, 1, true, 4);
        ITER(t + 2, 2, true, 4);
    }
    ITER(30, 0, false, 0);
    ITER(31, 1, false, -1);
#undef ITER
#undef STAGE

    // ---- epilogue: bias + exp + store + per-row exp-sum atomics
    int colb = lane & 15, rgrp = lane >> 4;
#pragma unroll
    for (int i = 0; i < 4; ++i) {
        float es0 = 0.f, es1 = 0.f, es2 = 0.f, es3 = 0.f;
        int gmb = m0 + wm * 64 + i * 16 + rgrp * 4;
#pragma unroll
        for (int j = 0; j < 4; ++j) {
            int gv = v0 + wn * 64 + j * 16 + colb;
            float bgj = bgen[gv];
            float v0f = acc[i][j][0] + bgj;
            float v1f = acc[i][j][1] + bgj;
            float v2f = acc[i][j][2] + bgj;
            float v3f = acc[i][j][3] + bgj;
            float e0 = __expf(v0f), e1 = __expf(v1f), e2 = __expf(v2f), e3 = __expf(v3f);
            if constexpr (EPI == 1) {
                ebuf[(size_t)(gmb + 0) * VV + gv] = f2bf(e0);
                ebuf[(size_t)(gmb + 1) * VV + gv] = f2bf(e1);
                ebuf[(size_t)(gmb + 2) * VV + gv] = f2bf(e2);
                ebuf[(size_t)(gmb + 3) * VV + gv] = f2bf(e3);
            } else {
                out[(size_t)(gmb + 0) * VV + gv] = v0f;
                out[(size_t)(gmb + 1) * VV + gv] = v1f;
                out[(size_t)(gmb + 2) * VV + gv] = v2f;
                out[(size_t)(gmb + 3) * VV + gv] = v3f;
            }
            es0 += e0; es1 += e1; es2 += e2; es3 += e3;
        }
        float es[4] = {es0, es1, es2, es3};
#pragma unroll
        for (int rr = 0; rr < 4; ++rr) {
            float e = es[rr];
            e += __shfl_xor(e, 1); e += __shfl_xor(e, 2);
            e += __shfl_xor(e, 4); e += __shfl_xor(e, 8);
            if (colb == 0) atomicAdd(&zg[gmb + rr], e);
        }
    }
}

// ---------------- fallback GEMM (f32 inputs, in-register cast, 128^2) ----------------
#define FBb 128
#define FLDK 40

__global__ __launch_bounds__(256) void k_gemm_f32(const float* __restrict__ A,
                                                  const float* __restrict__ Wg,
                                                  const float* __restrict__ bgen,
                                                  float* __restrict__ out,
                                                  float* __restrict__ zg) {
    __shared__ unsigned short As[FBb * FLDK];
    __shared__ unsigned short Bs[FBb * FLDK];
    int tid = threadIdx.x;
    int bid = blockIdx.x;
    int mt = bid & 7;
    int nt = bid >> 3;
    int m0 = mt * FBb, v0 = nt * FBb;
    int lane = tid & 63, wid = tid >> 6;
    int wr = (wid >> 1) * 64, wc = (wid & 1) * 64;
    int lr = lane & 15, lk = (lane >> 4) << 3;
    int r = tid >> 1, c0 = (tid & 1) << 4;

    f32x4 acc[4][4] = {};

    for (int k0 = 0; k0 < DD; k0 += 32) {
        {
            const float4* pa = reinterpret_cast<const float4*>(A + (size_t)(m0 + r) * DD + k0 + c0);
            float4 x0 = pa[0], x1 = pa[1], x2 = pa[2], x3 = pa[3];
            ushort8v u0, u1;
            u0[0] = f2bf(x0.x); u0[1] = f2bf(x0.y); u0[2] = f2bf(x0.z); u0[3] = f2bf(x0.w);
            u0[4] = f2bf(x1.x); u0[5] = f2bf(x1.y); u0[6] = f2bf(x1.z); u0[7] = f2bf(x1.w);
            u1[0] = f2bf(x2.x); u1[1] = f2bf(x2.y); u1[2] = f2bf(x2.z); u1[3] = f2bf(x2.w);
            u1[4] = f2bf(x3.x); u1[5] = f2bf(x3.y); u1[6] = f2bf(x3.z); u1[7] = f2bf(x3.w);
            *reinterpret_cast<ushort8v*>(&As[r * FLDK + c0]) = u0;
            *reinterpret_cast<ushort8v*>(&As[r * FLDK + c0 + 8]) = u1;

            const float4* pb = reinterpret_cast<const float4*>(Wg + (size_t)(v0 + r) * DD + k0 + c0);
            float4 y0 = pb[0], y1 = pb[1], y2 = pb[2], y3 = pb[3];
            ushort8v w0, w1;
            w0[0] = f2bf(y0.x); w0[1] = f2bf(y0.y); w0[2] = f2bf(y0.z); w0[3] = f2bf(y0.w);
            w0[4] = f2bf(y1.x); w0[5] = f2bf(y1.y); w0[6] = f2bf(y1.z); w0[7] = f2bf(y1.w);
            w1[0] = f2bf(y2.x); w1[1] = f2bf(y2.y); w1[2] = f2bf(y2.z); w1[3] = f2bf(y2.w);
            w1[4] = f2bf(y3.x); w1[5] = f2bf(y3.y); w1[6] = f2bf(y3.z); w1[7] = f2bf(y3.w);
            *reinterpret_cast<ushort8v*>(&Bs[r * FLDK + c0]) = w0;
            *reinterpret_cast<ushort8v*>(&Bs[r * FLDK + c0 + 8]) = w1;
        }
        __syncthreads();

        short8v af[4], bfr[4];
#pragma unroll
        for (int i = 0; i < 4; ++i)
            af[i] = *reinterpret_cast<const short8v*>(&As[(wr + i * 16 + lr) * FLDK + lk]);
#pragma unroll
        for (int j = 0; j < 4; ++j)
            bfr[j] = *reinterpret_cast<const short8v*>(&Bs[(wc + j * 16 + lr) * FLDK + lk]);
#pragma unroll
        for (int i = 0; i < 4; ++i)
#pragma unroll
            for (int j = 0; j < 4; ++j)
                acc[i][j] = __builtin_amdgcn_mfma_f32_16x16x32_bf16(af[i], bfr[j], acc[i][j], 0, 0, 0);
        __syncthreads();
    }

    int colb = lane & 15;
    int rgrp = lane >> 4;
#pragma unroll
    for (int i = 0; i < 4; ++i) {
        float es0 = 0.f, es1 = 0.f, es2 = 0.f, es3 = 0.f;
        int gmb = m0 + wr + i * 16 + rgrp * 4;
#pragma unroll
        for (int j = 0; j < 4; ++j) {
            int gv = v0 + wc + j * 16 + colb;
            float bgj = bgen[gv];
            float v0f = acc[i][j][0] + bgj;
            float v1f = acc[i][j][1] + bgj;
            float v2f = acc[i][j][2] + bgj;
            float v3f = acc[i][j][3] + bgj;
            out[(size_t)(gmb + 0) * VV + gv] = v0f;
            out[(size_t)(gmb + 1) * VV + gv] = v1f;
            out[(size_t)(gmb + 2) * VV + gv] = v2f;
            out[(size_t)(gmb + 3) * VV + gv] = v3f;
            es0 += __expf(v0f); es1 += __expf(v1f);
            es2 += __expf(v2f); es3 += __expf(v3f);
        }
        float es[4] = {es0, es1, es2, es3};
#pragma unroll
        for (int rr = 0; rr < 4; ++rr) {
            float e = es[rr];
            e += __shfl_xor(e, 1); e += __shfl_xor(e, 2);
            e += __shfl_xor(e, 4); e += __shfl_xor(e, 8);
            if (colb == 0) atomicAdd(&zg[gmb + rr], e);
        }
    }
}

// ---------------- merged row + final combine (512 threads, one block/row) ----------------
// Phase 1 = former k_row (thread-per-s, all in LDS). Phase 2 = combine.
// RD16=1: read bf16 exp(logit) from ebuf. RD16=0: read f32 logits in-place.
template <int RD16>
__global__ __launch_bounds__(512) void k_final(float* __restrict__ gen,
                                               const unsigned short* __restrict__ ebuf,
                                               const float* __restrict__ dattn,
                                               const int* __restrict__ src,
                                               const int* __restrict__ pos_map,
                                               const float* __restrict__ mw,
                                               const float* __restrict__ dw,
                                               const float* __restrict__ bprob,
                                               const float* __restrict__ zg) {
    int m = blockIdx.x;
    int b = m >> 7;
    int t = m & 127;
    int tid = threadIdx.x;
    __shared__ float a_row[SS];
    __shared__ float vals[SS];
    __shared__ int reps[SS];
    __shared__ float evs[SS];
    __shared__ float red[8];
    __shared__ float sA1, sA2, scc;

    // ---- phase 1: head mean (thread-per-s, coalesced across threads)
    {
        const float* base = dattn + ((size_t)b * HH * TT + t) * SS + tid;
        float sx = 0.f;
#pragma unroll
        for (int h = 0; h < HH; ++h) sx += base[(size_t)h * (TT * SS)];
        a_row[tid] = sx * 0.0625f;
        vals[tid] = 0.f;
        reps[tid] = pos_map[b * VV + src[b * SS + tid]];
    }
    __syncthreads();
    atomicAdd(&vals[reps[tid]], a_row[tid]);
    __syncthreads();
    float psum = a_row[tid] * mw[b * SS + tid];
    psum = block_sum8(psum, red, tid);
    float z = psum + dw[m] + bprob[0];
    float p = 1.0f / (1.0f + __expf(-z));
    float mxv = (reps[tid] == tid) ? vals[tid] : -3.4e38f;
    mxv = block_max8(mxv, red, tid);
    float m_c = fmaxf(0.0f, mxv);
    float sexp = 0.f, cnt = 0.f;
    {
        float e = 0.0f;
        if (reps[tid] == tid) {
            e = __expf(vals[tid] - m_c);
            sexp = e;
            cnt = 1.0f;
        }
        evs[tid] = e;
    }
    sexp = block_sum8(sexp, red, tid);
    cnt = block_sum8(cnt, red, tid);
    if (tid == 0) {
        float cc = __expf(-m_c);
        float zcv = ((float)VV - cnt) * cc + sexp;
        sA1 = p / zg[m];
        sA2 = (1.0f - p) / zcv;
        scc = cc;
    }
    __syncthreads();

    // ---- phase 2: combine into d_out
    float A1 = sA1, A2 = sA2, cc = scc;
    float4* row = reinterpret_cast<float4*>(gen + (size_t)m * VV);
    const int4* pm = reinterpret_cast<const int4*>(pos_map + b * VV);
    if constexpr (RD16 == 1) {
        const ushort8v* erow = reinterpret_cast<const ushort8v*>(ebuf + (size_t)m * VV);
        for (int i = tid; i < VV / 8; i += 512) {
            ushort8v ee = erow[i];
            int4 rp0 = pm[2 * i], rp1 = pm[2 * i + 1];
            float4 o0, o1;
            o0.x = __logf(A1 * bf2f(ee[0]) + A2 * ((rp0.x < SS) ? evs[rp0.x] : cc));
            o0.y = __logf(A1 * bf2f(ee[1]) + A2 * ((rp0.y < SS) ? evs[rp0.y] : cc));
            o0.z = __logf(A1 * bf2f(ee[2]) + A2 * ((rp0.z < SS) ? evs[rp0.z] : cc));
            o0.w = __logf(A1 * bf2f(ee[3]) + A2 * ((rp0.w < SS) ? evs[rp0.w] : cc));
            o1.x = __logf(A1 * bf2f(ee[4]) + A2 * ((rp1.x < SS) ? evs[rp1.x] : cc));
            o1.y = __logf(A1 * bf2f(ee[5]) + A2 * ((rp1.y < SS) ? evs[rp1.y] : cc));
            o1.z = __logf(A1 * bf2f(ee[6]) + A2 * ((rp1.z < SS) ? evs[rp1.z] : cc));
            o1.w = __logf(A1 * bf2f(ee[7]) + A2 * ((rp1.w < SS) ? evs[rp1.w] : cc));
            row[2 * i] = o0;
            row[2 * i + 1] = o1;
        }
    } else {
        for (int i = tid; i < VV / 4; i += 512) {
            float4 g = row[i];
            int4 rp = pm[i];
            float4 o;
            o.x = __logf(A1 * __expf(g.x) + A2 * ((rp.x < SS) ? evs[rp.x] : cc));
            o.y = __logf(A1 * __expf(g.y) + A2 * ((rp.y < SS) ? evs[rp.y] : cc));
            o.z = __logf(A1 * __expf(g.z) + A2 * ((rp.z < SS) ? evs[rp.z] : cc));
            o.w = __logf(A1 * __expf(g.w) + A2 * ((rp.w < SS) ? evs[rp.w] : cc));
            row[i] = o;
        }
    }
}

extern "C" void kernel_launch(void* const* d_in, const int* in_sizes, int n_in,
                              void* d_out, int out_size, void* d_ws, size_t ws_size,
                              hipStream_t stream) {
    const int* src = (const int*)d_in[0];
    const float* dec = (const float*)d_in[1];
    const float* dattn = (const float*)d_in[2];
    const float* mem = (const float*)d_in[3];
    const float* wgen = (const float*)d_in[4];
    const float* bgen = (const float*)d_in[5];
    const float* wprob = (const float*)d_in[6];
    const float* bprob = (const float*)d_in[7];
    float* out = (float*)d_out;
    char* ws = (char*)d_ws;

    // ws layout
    int* pos_map = (int*)(ws + 0);                       // 1,024,000 B (pad 1 MB)
    float* mw   = (float*)(ws + 1048576);                // 16 KB
    float* dw   = (float*)(ws + 1048576 + 16384);
    float* zg   = (float*)(ws + 1048576 + 24576);        // 4 KB
    unsigned short* Wbf = (unsigned short*)(ws + 1114112);              // 65,536,000 B
    unsigned short* Abf = (unsigned short*)(ws + 1114112 + 65536000);   // 2 MB
    unsigned short* Ebf = (unsigned short*)(ws + 1114112 + 65536000 + 2097152);  // 65,536,000 B
    const size_t NEEDED  = 1114112ull + 65536000ull + 2097152ull;
    const size_t NEEDED2 = NEEDED + 65536000ull;

    bool do_cast = ws_size >= NEEDED;

    // pos_map "infinity" = 0x7F7F7F7F (> any s in [0,512)); zg = 0.0f
    hipMemsetAsync(pos_map, 0x7F, (size_t)BB * VV * sizeof(int), stream);
    hipMemsetAsync(zg, 0, (size_t)MM * sizeof(float), stream);

    k_setup<<<do_cast ? 1704 : 648, 512, 0, stream>>>(
        src, pos_map, mem, dec, wprob, mw, dw, wgen,
        do_cast ? Wbf : nullptr, do_cast ? Abf : nullptr);

    if (do_cast) {
        if (ws_size >= NEEDED2) {
            k_gemm_bf<1><<<(MM / 128) * (VV / 128), 256, 0, stream>>>(Abf, Wbf, bgen, out, Ebf, zg);
            k_final<1><<<MM, 512, 0, stream>>>(out, Ebf, dattn, src, pos_map, mw, dw, bprob, zg);
        } else {
            k_gemm_bf<0><<<(MM / 128) * (VV / 128), 256, 0, stream>>>(Abf, Wbf, bgen, out, Ebf, zg);
            k_final<0><<<MM, 512, 0, stream>>>(out, Ebf, dattn, src, pos_map, mw, dw, bprob, zg);
        }
    } else {
        k_gemm_f32<<<(MM / FBb) * (VV / FBb), 256, 0, stream>>>(dec, wgen, bgen, out, zg);
        k_final<0><<<MM, 512, 0, stream>>>(out, Ebf, dattn, src, pos_map, mw, dw, bprob, zg);
    }
}

// Round 16
// 203.228 us; speedup vs baseline: 1.1078x; 1.0260x over previous
//
#include <hip/hip_runtime.h>
#include <hip/hip_bf16.h>
#include <cstddef>
#include <cstdint>

// Problem constants
#define BB 8
#define HH 16
#define TT 128
#define SS 512
#define DD 1024
#define VV 32000
#define MM (BB * TT)   // 1024 output rows

typedef float f32x4 __attribute__((ext_vector_type(4)));
typedef short short8v __attribute__((ext_vector_type(8)));
typedef unsigned short ushort8v __attribute__((ext_vector_type(8)));

__device__ __forceinline__ unsigned short f2bf(float x) {
    __hip_bfloat16 h = __float2bfloat16(x);
    return __builtin_bit_cast(unsigned short, h);
}
__device__ __forceinline__ float bf2f(unsigned short u) {
    unsigned int x = ((unsigned int)u) << 16;
    return __builtin_bit_cast(float, x);
}

__device__ __forceinline__ float wave_sum(float v) {
#pragma unroll
    for (int o = 1; o < 64; o <<= 1) v += __shfl_xor(v, o);
    return v;
}
__device__ __forceinline__ float wave_max(float v) {
#pragma unroll
    for (int o = 1; o < 64; o <<= 1) v = fmaxf(v, __shfl_xor(v, o));
    return v;
}
// 512-thread (8-wave) block reductions
__device__ __forceinline__ float block_sum8(float v, float* red, int tid) {
    v = wave_sum(v);
    __syncthreads();
    if ((tid & 63) == 0) red[tid >> 6] = v;
    __syncthreads();
    return red[0] + red[1] + red[2] + red[3] + red[4] + red[5] + red[6] + red[7];
}
__device__ __forceinline__ float block_max8(float v, float* red, int tid) {
    v = wave_max(v);
    __syncthreads();
    if ((tid & 63) == 0) red[tid >> 6] = v;
    __syncthreads();
    float a = fmaxf(fmaxf(red[0], red[1]), fmaxf(red[2], red[3]));
    float b = fmaxf(fmaxf(red[4], red[5]), fmaxf(red[6], red[7]));
    return fmaxf(a, b);
}

// ---------------- merged setup: pm_build | vecdots | cast-W | cast-A ----------------
// 512-thread blocks:
//   [0,8)        pm_build (pos_map pre-set to 0x7F7F7F7F by memset)
//   [8,648)      vecdots, 8 rows/block (5120 rows)
//   [648,1672)   cast W_gen f32->bf16, grid-stride (1024 blocks)  [if do_cast]
//   [1672,1704)  cast dec  f32->bf16, grid-stride (32 blocks)     [if do_cast]
__global__ __launch_bounds__(512) void k_setup(const int* __restrict__ src,
                                               int* __restrict__ pos_map,
                                               const float* __restrict__ memory,
                                               const float* __restrict__ dec,
                                               const float* __restrict__ wprob,
                                               float* __restrict__ mw,
                                               float* __restrict__ dw,
                                               const float* __restrict__ wgen,
                                               unsigned short* __restrict__ Wbf,
                                               unsigned short* __restrict__ Abf) {
    int blk = blockIdx.x, tid = threadIdx.x;
    if (blk < 8) {
        int tok = src[blk * SS + tid];
        atomicMin(&pos_map[blk * VV + tok], tid);
    } else if (blk < 648) {
        int row = (blk - 8) * 8 + (tid >> 6);
        int lane = tid & 63;
        const float4* srcv;
        const float4* wv;
        if (row < BB * SS) {
            srcv = reinterpret_cast<const float4*>(memory + (size_t)row * DD);
            wv = reinterpret_cast<const float4*>(wprob);
        } else {
            srcv = reinterpret_cast<const float4*>(dec + (size_t)(row - BB * SS) * DD);
            wv = reinterpret_cast<const float4*>(wprob + DD);
        }
        float sum = 0.f;
#pragma unroll
        for (int k = 0; k < 4; ++k) {
            int idx = lane + 64 * k;
            float4 a = srcv[idx];
            float4 w = wv[idx];
            sum += a.x * w.x + a.y * w.y + a.z * w.z + a.w * w.w;
        }
        sum = wave_sum(sum);
        if (lane == 0) {
            if (row < BB * SS) mw[row] = sum;
            else dw[row - BB * SS] = sum;
        }
    } else if (blk < 1672) {
        if (Wbf == nullptr) return;
        const int n8 = VV * DD / 8;
        for (int i = (blk - 648) * 512 + tid; i < n8; i += 1024 * 512) {
            const float4* p = reinterpret_cast<const float4*>(wgen + (size_t)i * 8);
            float4 a = p[0], b = p[1];
            ushort8v u;
            u[0] = f2bf(a.x); u[1] = f2bf(a.y); u[2] = f2bf(a.z); u[3] = f2bf(a.w);
            u[4] = f2bf(b.x); u[5] = f2bf(b.y); u[6] = f2bf(b.z); u[7] = f2bf(b.w);
            *reinterpret_cast<ushort8v*>(Wbf + (size_t)i * 8) = u;
        }
    } else {
        if (Abf == nullptr) return;
        const int n8 = MM * DD / 8;
        for (int i = (blk - 1672) * 512 + tid; i < n8; i += 32 * 512) {
            const float4* p = reinterpret_cast<const float4*>(dec + (size_t)i * 8);
            float4 a = p[0], b = p[1];
            ushort8v u;
            u[0] = f2bf(a.x); u[1] = f2bf(a.y); u[2] = f2bf(a.z); u[3] = f2bf(a.w);
            u[4] = f2bf(b.x); u[5] = f2bf(b.y); u[6] = f2bf(b.z); u[7] = f2bf(b.w);
            *reinterpret_cast<ushort8v*>(Abf + (size_t)i * 8) = u;
        }
    }
}

// =====================================================================
// 128x256 bf16 MFMA GEMM, 8 waves (64x64), BK=32, TRIPLE buffer, 2-deep
// prefetch, counted vmcnt(3). EXACT R14 configuration (measured 98.4-99.3
// us, VGPR 64, occupancy 33-34%, conflicts 0). R15's 128x128/4-wave
// variant REGRESSED (VGPR 96, occ 19%, 105 us) — reverted.
// Grid 1000 = 8 XCD x 125 bijective swizzle.
// =====================================================================
#define NKT 32          // K tiles = 1024/32
#define BUFE 12288      // elems per buffer: A 128*32=4096 + B 256*32=8192

#define AS1 __attribute__((address_space(1)))
#define AS3 __attribute__((address_space(3)))

template <int EPI>
__global__ __launch_bounds__(512, 4) void k_gemm_bf(const unsigned short* __restrict__ Abf,
                                                    const unsigned short* __restrict__ Wbf,
                                                    const float* __restrict__ bgen,
                                                    float* __restrict__ out,
                                                    unsigned short* __restrict__ ebuf,
                                                    float* __restrict__ zg) {
    __shared__ unsigned short lds[3 * BUFE];   // 72 KiB

    int tid = threadIdx.x;
    int p = blockIdx.x;
    // bijective XCD swizzle: 1000 = 8 * 125
    int wgid = (p & 7) * 125 + (p >> 3);
    int mt = wgid & 7, nt = wgid >> 3;   // consecutive wg share nt -> W L2 reuse
    int m0 = mt * 128, v0 = nt * 256;

    int lane = tid & 63, w = tid >> 6;
    int wm = w & 1, wn = w >> 1;         // wave owns 64(M) x 64(N)

    // staging: pre-swizzled source chunk ((tid&3)^((tid>>3)&3)), linear LDS dest
    int srow = tid >> 2;                 // 0..127
    int schunk = (tid & 3) ^ ((tid >> 3) & 3);
    const unsigned short* gA = Abf + (size_t)(m0 + srow) * DD + schunk * 8;
    const unsigned short* gB = Wbf + (size_t)(v0 + srow) * DD + schunk * 8;

    // per tile: 1 A-load + 2 B-loads per thread (vmcnt granularity = 3)
#define STAGE(T, BI) do {                                                              \
    size_t ko_ = (size_t)(T) * 32;                                                     \
    __builtin_amdgcn_global_load_lds(                                                  \
        (const AS1 void*)(gA + ko_),                                                   \
        (AS3 void*)(lds + (BI) * BUFE + tid * 8), 16, 0, 0);                           \
    __builtin_amdgcn_global_load_lds(                                                  \
        (const AS1 void*)(gB + ko_),                                                   \
        (AS3 void*)(lds + (BI) * BUFE + 4096 + tid * 8), 16, 0, 0);                    \
    __builtin_amdgcn_global_load_lds(                                                  \
        (const AS1 void*)(gB + (size_t)128 * DD + ko_),                                \
        (AS3 void*)(lds + (BI) * BUFE + 8192 + tid * 8), 16, 0, 0);                    \
} while (0)

    // fragment reads: row base multiple of 16 -> xr depends only on lr
    int lr = lane & 15, kg = lane >> 4;
    int xr = (lr >> 1) & 3;
    const unsigned short* arow = lds + (wm * 64 + lr) * 32 + ((kg ^ xr) << 3);
    const unsigned short* brow = lds + 4096 + (wn * 64 + lr) * 32 + ((kg ^ xr) << 3);

    f32x4 acc[4][4] = {};

#define ITER(T, BI, DO_STAGE, VM)  do {                                                \
    __builtin_amdgcn_s_barrier();                                                      \
    short8v af[4], bfr[4];                                                             \
    _Pragma("unroll")                                                                  \
    for (int i = 0; i < 4; ++i) {                                                      \
        af[i] = *reinterpret_cast<const short8v*>(arow + (BI) * BUFE + i * 512);       \
        bfr[i] = *reinterpret_cast<const short8v*>(brow + (BI) * BUFE + i * 512);      \
    }                                                                                  \
    if (DO_STAGE) STAGE((T) + 2, ((BI) + 2) % 3);                                      \
    __builtin_amdgcn_s_setprio(1);                                                     \
    _Pragma("unroll")                                                                  \
    for (int i = 0; i < 4; ++i)                                                        \
        _Pragma("unroll")                                                              \
        for (int j = 0; j < 4; ++j)                                                    \
            acc[i][j] = __builtin_amdgcn_mfma_f32_16x16x32_bf16(af[i], bfr[j], acc[i][j], 0, 0, 0); \
    __builtin_amdgcn_s_setprio(0);                                                     \
    if ((VM) == 3) asm volatile("s_waitcnt vmcnt(3)" ::: "memory");                    \
    else if ((VM) == 0) asm volatile("s_waitcnt vmcnt(0)" ::: "memory");               \
} while (0)

    // prologue: stage tiles 0,1; wait tile 0 (3 newest = tile 1 still in flight)
    STAGE(0, 0);
    STAGE(1, 1);
    asm volatile("s_waitcnt vmcnt(3)" ::: "memory");

    for (int t = 0; t < NKT - 2; t += 3) {
        ITER(t + 0, 0, true, 3);
        ITER(t + 1, 1, true, 3);
        ITER(t + 2, 2, true, 3);
    }
    ITER(30, 0, false, 0);
    ITER(31, 1, false, -1);
#undef ITER
#undef STAGE

    // ---- epilogue: bias + exp + store + per-row exp-sum atomics
    int colb = lane & 15, rgrp = lane >> 4;
#pragma unroll
    for (int i = 0; i < 4; ++i) {
        float es0 = 0.f, es1 = 0.f, es2 = 0.f, es3 = 0.f;
        int gmb = m0 + wm * 64 + i * 16 + rgrp * 4;
#pragma unroll
        for (int j = 0; j < 4; ++j) {
            int gv = v0 + wn * 64 + j * 16 + colb;
            float bgj = bgen[gv];
            float v0f = acc[i][j][0] + bgj;
            float v1f = acc[i][j][1] + bgj;
            float v2f = acc[i][j][2] + bgj;
            float v3f = acc[i][j][3] + bgj;
            float e0 = __expf(v0f), e1 = __expf(v1f), e2 = __expf(v2f), e3 = __expf(v3f);
            if constexpr (EPI == 1) {
                ebuf[(size_t)(gmb + 0) * VV + gv] = f2bf(e0);
                ebuf[(size_t)(gmb + 1) * VV + gv] = f2bf(e1);
                ebuf[(size_t)(gmb + 2) * VV + gv] = f2bf(e2);
                ebuf[(size_t)(gmb + 3) * VV + gv] = f2bf(e3);
            } else {
                out[(size_t)(gmb + 0) * VV + gv] = v0f;
                out[(size_t)(gmb + 1) * VV + gv] = v1f;
                out[(size_t)(gmb + 2) * VV + gv] = v2f;
                out[(size_t)(gmb + 3) * VV + gv] = v3f;
            }
            es0 += e0; es1 += e1; es2 += e2; es3 += e3;
        }
        float es[4] = {es0, es1, es2, es3};
#pragma unroll
        for (int rr = 0; rr < 4; ++rr) {
            float e = es[rr];
            e += __shfl_xor(e, 1); e += __shfl_xor(e, 2);
            e += __shfl_xor(e, 4); e += __shfl_xor(e, 8);
            if (colb == 0) atomicAdd(&zg[gmb + rr], e);
        }
    }
}

// ---------------- fallback GEMM (f32 inputs, in-register cast, 128^2) ----------------
#define FBb 128
#define FLDK 40

__global__ __launch_bounds__(256) void k_gemm_f32(const float* __restrict__ A,
                                                  const float* __restrict__ Wg,
                                                  const float* __restrict__ bgen,
                                                  float* __restrict__ out,
                                                  float* __restrict__ zg) {
    __shared__ unsigned short As[FBb * FLDK];
    __shared__ unsigned short Bs[FBb * FLDK];
    int tid = threadIdx.x;
    int bid = blockIdx.x;
    int mt = bid & 7;
    int nt = bid >> 3;
    int m0 = mt * FBb, v0 = nt * FBb;
    int lane = tid & 63, wid = tid >> 6;
    int wr = (wid >> 1) * 64, wc = (wid & 1) * 64;
    int lr = lane & 15, lk = (lane >> 4) << 3;
    int r = tid >> 1, c0 = (tid & 1) << 4;

    f32x4 acc[4][4] = {};

    for (int k0 = 0; k0 < DD; k0 += 32) {
        {
            const float4* pa = reinterpret_cast<const float4*>(A + (size_t)(m0 + r) * DD + k0 + c0);
            float4 x0 = pa[0], x1 = pa[1], x2 = pa[2], x3 = pa[3];
            ushort8v u0, u1;
            u0[0] = f2bf(x0.x); u0[1] = f2bf(x0.y); u0[2] = f2bf(x0.z); u0[3] = f2bf(x0.w);
            u0[4] = f2bf(x1.x); u0[5] = f2bf(x1.y); u0[6] = f2bf(x1.z); u0[7] = f2bf(x1.w);
            u1[0] = f2bf(x2.x); u1[1] = f2bf(x2.y); u1[2] = f2bf(x2.z); u1[3] = f2bf(x2.w);
            u1[4] = f2bf(x3.x); u1[5] = f2bf(x3.y); u1[6] = f2bf(x3.z); u1[7] = f2bf(x3.w);
            *reinterpret_cast<ushort8v*>(&As[r * FLDK + c0]) = u0;
            *reinterpret_cast<ushort8v*>(&As[r * FLDK + c0 + 8]) = u1;

            const float4* pb = reinterpret_cast<const float4*>(Wg + (size_t)(v0 + r) * DD + k0 + c0);
            float4 y0 = pb[0], y1 = pb[1], y2 = pb[2], y3 = pb[3];
            ushort8v w0, w1;
            w0[0] = f2bf(y0.x); w0[1] = f2bf(y0.y); w0[2] = f2bf(y0.z); w0[3] = f2bf(y0.w);
            w0[4] = f2bf(y1.x); w0[5] = f2bf(y1.y); w0[6] = f2bf(y1.z); w0[7] = f2bf(y1.w);
            w1[0] = f2bf(y2.x); w1[1] = f2bf(y2.y); w1[2] = f2bf(y2.z); w1[3] = f2bf(y2.w);
            w1[4] = f2bf(y3.x); w1[5] = f2bf(y3.y); w1[6] = f2bf(y3.z); w1[7] = f2bf(y3.w);
            *reinterpret_cast<ushort8v*>(&Bs[r * FLDK + c0]) = w0;
            *reinterpret_cast<ushort8v*>(&Bs[r * FLDK + c0 + 8]) = w1;
        }
        __syncthreads();

        short8v af[4], bfr[4];
#pragma unroll
        for (int i = 0; i < 4; ++i)
            af[i] = *reinterpret_cast<const short8v*>(&As[(wr + i * 16 + lr) * FLDK + lk]);
#pragma unroll
        for (int j = 0; j < 4; ++j)
            bfr[j] = *reinterpret_cast<const short8v*>(&Bs[(wc + j * 16 + lr) * FLDK + lk]);
#pragma unroll
        for (int i = 0; i < 4; ++i)
#pragma unroll
            for (int j = 0; j < 4; ++j)
                acc[i][j] = __builtin_amdgcn_mfma_f32_16x16x32_bf16(af[i], bfr[j], acc[i][j], 0, 0, 0);
        __syncthreads();
    }

    int colb = lane & 15;
    int rgrp = lane >> 4;
#pragma unroll
    for (int i = 0; i < 4; ++i) {
        float es0 = 0.f, es1 = 0.f, es2 = 0.f, es3 = 0.f;
        int gmb = m0 + wr + i * 16 + rgrp * 4;
#pragma unroll
        for (int j = 0; j < 4; ++j) {
            int gv = v0 + wc + j * 16 + colb;
            float bgj = bgen[gv];
            float v0f = acc[i][j][0] + bgj;
            float v1f = acc[i][j][1] + bgj;
            float v2f = acc[i][j][2] + bgj;
            float v3f = acc[i][j][3] + bgj;
            out[(size_t)(gmb + 0) * VV + gv] = v0f;
            out[(size_t)(gmb + 1) * VV + gv] = v1f;
            out[(size_t)(gmb + 2) * VV + gv] = v2f;
            out[(size_t)(gmb + 3) * VV + gv] = v3f;
            es0 += __expf(v0f); es1 += __expf(v1f);
            es2 += __expf(v2f); es3 += __expf(v3f);
        }
        float es[4] = {es0, es1, es2, es3};
#pragma unroll
        for (int rr = 0; rr < 4; ++rr) {
            float e = es[rr];
            e += __shfl_xor(e, 1); e += __shfl_xor(e, 2);
            e += __shfl_xor(e, 4); e += __shfl_xor(e, 8);
            if (colb == 0) atomicAdd(&zg[gmb + rr], e);
        }
    }
}

// ---------------- merged row + final combine (512 threads, one block/row) ----------------
// Phase 1 = former k_row (thread-per-s, all in LDS). Phase 2 = combine.
// RD16=1: read bf16 exp(logit) from ebuf. RD16=0: read f32 logits in-place.
template <int RD16>
__global__ __launch_bounds__(512) void k_final(float* __restrict__ gen,
                                               const unsigned short* __restrict__ ebuf,
                                               const float* __restrict__ dattn,
                                               const int* __restrict__ src,
                                               const int* __restrict__ pos_map,
                                               const float* __restrict__ mw,
                                               const float* __restrict__ dw,
                                               const float* __restrict__ bprob,
                                               const float* __restrict__ zg) {
    int m = blockIdx.x;
    int b = m >> 7;
    int t = m & 127;
    int tid = threadIdx.x;
    __shared__ float a_row[SS];
    __shared__ float vals[SS];
    __shared__ int reps[SS];
    __shared__ float evs[SS];
    __shared__ float red[8];
    __shared__ float sA1, sA2, scc;

    // ---- phase 1: head mean (thread-per-s, coalesced across threads)
    {
        const float* base = dattn + ((size_t)b * HH * TT + t) * SS + tid;
        float sx = 0.f;
#pragma unroll
        for (int h = 0; h < HH; ++h) sx += base[(size_t)h * (TT * SS)];
        a_row[tid] = sx * 0.0625f;
        vals[tid] = 0.f;
        reps[tid] = pos_map[b * VV + src[b * SS + tid]];
    }
    __syncthreads();
    atomicAdd(&vals[reps[tid]], a_row[tid]);
    __syncthreads();
    float psum = a_row[tid] * mw[b * SS + tid];
    psum = block_sum8(psum, red, tid);
    float z = psum + dw[m] + bprob[0];
    float p = 1.0f / (1.0f + __expf(-z));
    float mxv = (reps[tid] == tid) ? vals[tid] : -3.4e38f;
    mxv = block_max8(mxv, red, tid);
    float m_c = fmaxf(0.0f, mxv);
    float sexp = 0.f, cnt = 0.f;
    {
        float e = 0.0f;
        if (reps[tid] == tid) {
            e = __expf(vals[tid] - m_c);
            sexp = e;
            cnt = 1.0f;
        }
        evs[tid] = e;
    }
    sexp = block_sum8(sexp, red, tid);
    cnt = block_sum8(cnt, red, tid);
    if (tid == 0) {
        float cc = __expf(-m_c);
        float zcv = ((float)VV - cnt) * cc + sexp;
        sA1 = p / zg[m];
        sA2 = (1.0f - p) / zcv;
        scc = cc;
    }
    __syncthreads();

    // ---- phase 2: combine into d_out
    float A1 = sA1, A2 = sA2, cc = scc;
    float4* row = reinterpret_cast<float4*>(gen + (size_t)m * VV);
    const int4* pm = reinterpret_cast<const int4*>(pos_map + b * VV);
    if constexpr (RD16 == 1) {
        const ushort8v* erow = reinterpret_cast<const ushort8v*>(ebuf + (size_t)m * VV);
        for (int i = tid; i < VV / 8; i += 512) {
            ushort8v ee = erow[i];
            int4 rp0 = pm[2 * i], rp1 = pm[2 * i + 1];
            float4 o0, o1;
            o0.x = __logf(A1 * bf2f(ee[0]) + A2 * ((rp0.x < SS) ? evs[rp0.x] : cc));
            o0.y = __logf(A1 * bf2f(ee[1]) + A2 * ((rp0.y < SS) ? evs[rp0.y] : cc));
            o0.z = __logf(A1 * bf2f(ee[2]) + A2 * ((rp0.z < SS) ? evs[rp0.z] : cc));
            o0.w = __logf(A1 * bf2f(ee[3]) + A2 * ((rp0.w < SS) ? evs[rp0.w] : cc));
            o1.x = __logf(A1 * bf2f(ee[4]) + A2 * ((rp1.x < SS) ? evs[rp1.x] : cc));
            o1.y = __logf(A1 * bf2f(ee[5]) + A2 * ((rp1.y < SS) ? evs[rp1.y] : cc));
            o1.z = __logf(A1 * bf2f(ee[6]) + A2 * ((rp1.z < SS) ? evs[rp1.z] : cc));
            o1.w = __logf(A1 * bf2f(ee[7]) + A2 * ((rp1.w < SS) ? evs[rp1.w] : cc));
            row[2 * i] = o0;
            row[2 * i + 1] = o1;
        }
    } else {
        for (int i = tid; i < VV / 4; i += 512) {
            float4 g = row[i];
            int4 rp = pm[i];
            float4 o;
            o.x = __logf(A1 * __expf(g.x) + A2 * ((rp.x < SS) ? evs[rp.x] : cc));
            o.y = __logf(A1 * __expf(g.y) + A2 * ((rp.y < SS) ? evs[rp.y] : cc));
            o.z = __logf(A1 * __expf(g.z) + A2 * ((rp.z < SS) ? evs[rp.z] : cc));
            o.w = __logf(A1 * __expf(g.w) + A2 * ((rp.w < SS) ? evs[rp.w] : cc));
            row[i] = o;
        }
    }
}

extern "C" void kernel_launch(void* const* d_in, const int* in_sizes, int n_in,
                              void* d_out, int out_size, void* d_ws, size_t ws_size,
                              hipStream_t stream) {
    const int* src = (const int*)d_in[0];
    const float* dec = (const float*)d_in[1];
    const float* dattn = (const float*)d_in[2];
    const float* mem = (const float*)d_in[3];
    const float* wgen = (const float*)d_in[4];
    const float* bgen = (const float*)d_in[5];
    const float* wprob = (const float*)d_in[6];
    const float* bprob = (const float*)d_in[7];
    float* out = (float*)d_out;
    char* ws = (char*)d_ws;

    // ws layout
    int* pos_map = (int*)(ws + 0);                       // 1,024,000 B (pad 1 MB)
    float* mw   = (float*)(ws + 1048576);                // 16 KB
    float* dw   = (float*)(ws + 1048576 + 16384);
    float* zg   = (float*)(ws + 1048576 + 24576);        // 4 KB
    unsigned short* Wbf = (unsigned short*)(ws + 1114112);              // 65,536,000 B
    unsigned short* Abf = (unsigned short*)(ws + 1114112 + 65536000);   // 2 MB
    unsigned short* Ebf = (unsigned short*)(ws + 1114112 + 65536000 + 2097152);  // 65,536,000 B
    const size_t NEEDED  = 1114112ull + 65536000ull + 2097152ull;
    const size_t NEEDED2 = NEEDED + 65536000ull;

    bool do_cast = ws_size >= NEEDED;

    // pos_map "infinity" = 0x7F7F7F7F (> any s in [0,512)); zg = 0.0f
    hipMemsetAsync(pos_map, 0x7F, (size_t)BB * VV * sizeof(int), stream);
    hipMemsetAsync(zg, 0, (size_t)MM * sizeof(float), stream);

    k_setup<<<do_cast ? 1704 : 648, 512, 0, stream>>>(
        src, pos_map, mem, dec, wprob, mw, dw, wgen,
        do_cast ? Wbf : nullptr, do_cast ? Abf : nullptr);

    if (do_cast) {
        if (ws_size >= NEEDED2) {
            k_gemm_bf<1><<<(MM / 128) * (VV / 256), 512, 0, stream>>>(Abf, Wbf, bgen, out, Ebf, zg);
            k_final<1><<<MM, 512, 0, stream>>>(out, Ebf, dattn, src, pos_map, mw, dw, bprob, zg);
        } else {
            k_gemm_bf<0><<<(MM / 128) * (VV / 256), 512, 0, stream>>>(Abf, Wbf, bgen, out, Ebf, zg);
            k_final<0><<<MM, 512, 0, stream>>>(out, Ebf, dattn, src, pos_map, mw, dw, bprob, zg);
        }
    } else {
        k_gemm_f32<<<(MM / FBb) * (VV / FBb), 256, 0, stream>>>(dec, wgen, bgen, out, zg);
        k_final<0><<<MM, 512, 0, stream>>>(out, Ebf, dattn, src, pos_map, mw, dw, bprob, zg);
    }
}